// Round 1
// baseline (1703.798 us; speedup 1.0000x reference)
//
#include <hip/hip_runtime.h>
#include <math.h>

#define BN_EPS 1e-5f

// ---------------- conv 3x3 stride1 pad1 + bias + BN + ReLU ----------------
template<int C, int O, int H, int W>
__global__ __launch_bounds__(256)
void conv3s1_bn_relu(const float* __restrict__ x, const float* __restrict__ w,
                     const float* __restrict__ bias,
                     const float* __restrict__ g, const float* __restrict__ be,
                     const float* __restrict__ m, const float* __restrict__ v,
                     float* __restrict__ out)
{
    int idx = blockIdx.x * 256 + threadIdx.x;
    int j = idx % W;
    int i = (idx / W) % H;
    int o = (idx / (W * H)) % O;
    int b = idx / (W * H * O);
    float acc = bias[o];
    for (int kh = 0; kh < 3; ++kh) {
        int ih = i - 1 + kh;
        if (ih < 0 || ih >= H) continue;
        for (int kw = 0; kw < 3; ++kw) {
            int iw = j - 1 + kw;
            if (iw < 0 || iw >= W) continue;
            const float* xq = x + ((size_t)b * C * H + ih) * W + iw;
            const float* wq = w + o * C * 9 + kh * 3 + kw;
            #pragma unroll
            for (int c = 0; c < C; ++c)
                acc = fmaf(xq[(size_t)c * H * W], wq[c * 9], acc);
        }
    }
    float sc = g[o] * rsqrtf(v[o] + BN_EPS);
    float sh = be[o] - m[o] * sc;
    out[idx] = fmaxf(fmaf(acc, sc, sh), 0.f);
}

// ---------------- offset conv: 3x3, pad 1, stride S, with bias ----------------
template<int C, int H, int W, int OH, int OW, int S>
__global__ __launch_bounds__(256)
void offset_conv(const float* __restrict__ x, const float* __restrict__ wp,
                 const float* __restrict__ bp, float* __restrict__ out)
{
    int idx = blockIdx.x * 256 + threadIdx.x;
    int j = idx % OW;
    int i = (idx / OW) % OH;
    int mch = (idx / (OW * OH)) % 18;
    int b = idx / (OW * OH * 18);
    float acc = bp[mch];
    for (int kh = 0; kh < 3; ++kh) {
        int ih = i * S - 1 + kh;
        if (ih < 0 || ih >= H) continue;
        for (int kw = 0; kw < 3; ++kw) {
            int iw = j * S - 1 + kw;
            if (iw < 0 || iw >= W) continue;
            const float* xq = x + ((size_t)b * C * H + ih) * W + iw;
            const float* wq = wp + mch * C * 9 + kh * 3 + kw;
            for (int c = 0; c < C; ++c)
                acc = fmaf(xq[(size_t)c * H * W], wq[c * 9], acc);
        }
    }
    out[idx] = acc;
}

// ---------------- fused deform-gather + GEMM + BN + ReLU ----------------
// out[p, o] = sum_k xoff[p, k] * wc[o, k],  p=(b,i,j), k=c*9+n, K=C*9
// Bilinear sample table (positions shared across channels) built once per
// 64-pixel block; A-tile elements gathered on demand.
template<int C, int O, int H, int W, int OH, int OW, int S>
__global__ __launch_bounds__(256)
void deform_gemm_bn_relu(const float* __restrict__ x, const float* __restrict__ off,
                         const float* __restrict__ wc,
                         const float* __restrict__ g, const float* __restrict__ be,
                         const float* __restrict__ m, const float* __restrict__ v,
                         float* __restrict__ out)
{
    constexpr int K  = C * 9;
    constexpr int BM = 64;
    constexpr int BK = 32;
    constexpr int BN = O;
    constexpr int OPT = 8;              // outputs per thread
    constexpr int TCOLS = BN / OPT;     // 8 (O=64) or 16 (O=128)
    constexpr int TROWS = 256 / TCOLS;  // 32 or 16
    constexpr int PPT = BM / TROWS;     // 2 or 4 pixels per thread
    constexpr int Hp = H + 2, Wp = W + 2;

    __shared__ int4   tbl_idx[BM][9];
    __shared__ float4 tbl_w[BM][9];
    __shared__ int    pix_base[BM];
    __shared__ __align__(16) float A_t[BK][BM + 4];   // [kk][lp]
    __shared__ __align__(16) float B_t[BK][BN + 4];   // [kk][o]

    const int tid = threadIdx.x;
    const int p0 = blockIdx.x * BM;

    // ---- build bilinear sample table ----
    for (int e = tid; e < BM * 9; e += 256) {
        int lp = e / 9, n = e % 9;
        int p = p0 + lp;
        int b = p / (OH * OW);
        int rem = p % (OH * OW);
        int i = rem / OW, j = rem % OW;
        if (n == 0) pix_base[lp] = b * (C * H * W);
        float ox = off[((size_t)(b * 18 + n) * OH + i) * OW + j];
        float oy = off[((size_t)(b * 18 + 9 + n) * OH + i) * OW + j];
        float px = (float)(i * S + (n / 3)) + ox;      // 1 + i*S + (n/3 - 1)
        float py = (float)(j * S + (n % 3)) + oy;
        int qx0 = (int)floorf(px);
        int qy0 = (int)floorf(py);
        int x0 = min(max(qx0, 0), Hp - 1);
        int x1 = min(max(qx0 + 1, 0), Hp - 1);
        int y0 = min(max(qy0, 0), Wp - 1);
        int y1 = min(max(qy0 + 1, 0), Wp - 1);
        float pxc = fminf(fmaxf(px, 0.f), (float)(Hp - 1));
        float pyc = fminf(fmaxf(py, 0.f), (float)(Wp - 1));
        float gx0 = 1.f + ((float)x0 - pxc);
        float gx1 = 1.f - ((float)x1 - pxc);
        float gy0 = 1.f + ((float)y0 - pyc);
        float gy1 = 1.f - ((float)y1 - pyc);
        // padded->unpadded (pad=1); -1 marks a zero (padding) tap
        int u0 = x0 - 1, u1 = x1 - 1, v0 = y0 - 1, v1 = y1 - 1;
        int4 ti;
        ti.x = (u0 >= 0 && u0 < H && v0 >= 0 && v0 < W) ? u0 * W + v0 : -1;
        ti.y = (u1 >= 0 && u1 < H && v1 >= 0 && v1 < W) ? u1 * W + v1 : -1;
        ti.z = (u0 >= 0 && u0 < H && v1 >= 0 && v1 < W) ? u0 * W + v1 : -1;
        ti.w = (u1 >= 0 && u1 < H && v0 >= 0 && v0 < W) ? u1 * W + v0 : -1;
        tbl_idx[lp][n] = ti;
        tbl_w[lp][n] = make_float4(gx0 * gy0, gx1 * gy1, gx0 * gy1, gx1 * gy0);
    }
    __syncthreads();

    float acc[PPT][OPT];
    #pragma unroll
    for (int a = 0; a < PPT; ++a)
        #pragma unroll
        for (int bb = 0; bb < OPT; ++bb) acc[a][bb] = 0.f;

    const int tr = tid / TCOLS, tc = tid % TCOLS;
    const int lp_base = tr * PPT;
    const int o_base = tc * OPT;
    const int kkA = tid % BK;    // fixed k-column for A staging
    const int lpA0 = tid / BK;   // pixels lpA0 + 8*r

    for (int k0 = 0; k0 < K; k0 += BK) {
        // ---- stage A tile (bilinear gather) ----
        {
            int k = k0 + kkA;
            int c = k / 9, n = k % 9;
            #pragma unroll
            for (int r = 0; r < BM / 8; ++r) {
                int lp = lpA0 + 8 * r;
                const float* plane = x + pix_base[lp] + c * H * W;
                int4 ti = tbl_idx[lp][n];
                float4 tw = tbl_w[lp][n];
                float val = 0.f;
                if (ti.x >= 0) val = fmaf(tw.x, plane[ti.x], val);
                if (ti.y >= 0) val = fmaf(tw.y, plane[ti.y], val);
                if (ti.z >= 0) val = fmaf(tw.z, plane[ti.z], val);
                if (ti.w >= 0) val = fmaf(tw.w, plane[ti.w], val);
                A_t[kkA][lp] = val;
            }
        }
        // ---- stage B tile (weights, coalesced over k) ----
        for (int e = tid; e < BK * BN; e += 256) {
            int o = e / BK;
            int kk = e % BK;
            B_t[kk][o] = wc[(size_t)o * K + k0 + kk];
        }
        __syncthreads();
        // ---- micro-tile FMA ----
        #pragma unroll
        for (int kk = 0; kk < BK; ++kk) {
            float a[PPT], bb[OPT];
            *(float4*)&bb[0] = *(const float4*)&B_t[kk][o_base];
            *(float4*)&bb[4] = *(const float4*)&B_t[kk][o_base + 4];
            if constexpr (PPT == 4) {
                *(float4*)&a[0] = *(const float4*)&A_t[kk][lp_base];
            } else {
                *(float2*)&a[0] = *(const float2*)&A_t[kk][lp_base];
            }
            #pragma unroll
            for (int up = 0; up < PPT; ++up)
                #pragma unroll
                for (int uo = 0; uo < OPT; ++uo)
                    acc[up][uo] = fmaf(a[up], bb[uo], acc[up][uo]);
        }
        __syncthreads();
    }

    // ---- epilogue: BN + ReLU, write NCHW ----
    #pragma unroll
    for (int uo = 0; uo < OPT; ++uo) {
        int o = o_base + uo;
        float sc = g[o] * rsqrtf(v[o] + BN_EPS);
        float sh = be[o] - m[o] * sc;
        #pragma unroll
        for (int up = 0; up < PPT; ++up) {
            int p = p0 + lp_base + up;
            int b = p / (OH * OW);
            int rem = p % (OH * OW);
            float val = fmaf(acc[up][uo], sc, sh);
            out[(size_t)(b * O + o) * (OH * OW) + rem] = fmaxf(val, 0.f);
        }
    }
}

// ---------------- global avg pool (8x8) + FC 128->100 ----------------
__global__ __launch_bounds__(128)
void pool_fc(const float* __restrict__ h4, const float* __restrict__ wcls,
             const float* __restrict__ bcls, float* __restrict__ out)
{
    __shared__ float pool[128];
    int b = blockIdx.x;
    int tid = threadIdx.x;   // 128 threads, one per channel
    const float* src = h4 + ((size_t)b * 128 + tid) * 64;
    float s = 0.f;
    #pragma unroll
    for (int t = 0; t < 64; ++t) s += src[t];
    pool[tid] = s * (1.f / 64.f);
    __syncthreads();
    if (tid < 100) {
        float acc = bcls[tid];
        const float* wr = wcls + tid * 128;
        #pragma unroll
        for (int c = 0; c < 128; ++c) acc = fmaf(pool[c], wr[c], acc);
        out[(size_t)b * 100 + tid] = acc;
    }
}

extern "C" void kernel_launch(void* const* d_in, const int* in_sizes, int n_in,
                              void* d_out, int out_size, void* d_ws, size_t ws_size,
                              hipStream_t stream)
{
    const float* x    = (const float*)d_in[0];
    const float* w1   = (const float*)d_in[1];
    const float* b1   = (const float*)d_in[2];
    const float* g1   = (const float*)d_in[3];
    const float* be1  = (const float*)d_in[4];
    const float* m1   = (const float*)d_in[5];
    const float* v1   = (const float*)d_in[6];
    const float* wp2  = (const float*)d_in[7];
    const float* bp2  = (const float*)d_in[8];
    const float* wc2  = (const float*)d_in[9];
    const float* g2   = (const float*)d_in[10];
    const float* be2  = (const float*)d_in[11];
    const float* m2   = (const float*)d_in[12];
    const float* v2   = (const float*)d_in[13];
    const float* wp3  = (const float*)d_in[14];
    const float* bp3  = (const float*)d_in[15];
    const float* wc3  = (const float*)d_in[16];
    const float* g3   = (const float*)d_in[17];
    const float* be3  = (const float*)d_in[18];
    const float* m3   = (const float*)d_in[19];
    const float* v3   = (const float*)d_in[20];
    const float* wp4  = (const float*)d_in[21];
    const float* bp4  = (const float*)d_in[22];
    const float* wc4  = (const float*)d_in[23];
    const float* g4   = (const float*)d_in[24];
    const float* be4  = (const float*)d_in[25];
    const float* m4   = (const float*)d_in[26];
    const float* v4   = (const float*)d_in[27];
    const float* wcls = (const float*)d_in[28];
    const float* bcls = (const float*)d_in[29];
    float* out = (float*)d_out;

    float* ws  = (float*)d_ws;
    float* h1  = ws;                  // 256*32*32*32 = 8,388,608
    float* off = h1 + 8388608;        // max 256*18*16*16 = 1,179,648 (reused)
    float* h2  = off + 1179648;       // 256*64*16*16 = 4,194,304
    float* h3  = h2 + 4194304;        // 256*128*16*16 = 8,388,608
    float* h4  = h3 + 8388608;        // 256*128*8*8 = 2,097,152
    (void)ws_size; (void)in_sizes; (void)n_in; (void)out_size;

    // Layer 1: conv 3->32, 32x32
    conv3s1_bn_relu<3, 32, 32, 32><<<32768, 256, 0, stream>>>(
        x, w1, b1, g1, be1, m1, v1, h1);

    // Layer 2: deform 32->64, 32x32 -> 16x16, stride 2
    offset_conv<32, 32, 32, 16, 16, 2><<<4608, 256, 0, stream>>>(h1, wp2, bp2, off);
    deform_gemm_bn_relu<32, 64, 32, 32, 16, 16, 2><<<1024, 256, 0, stream>>>(
        h1, off, wc2, g2, be2, m2, v2, h2);

    // Layer 3: deform 64->128, 16x16 -> 16x16, stride 1
    offset_conv<64, 16, 16, 16, 16, 1><<<4608, 256, 0, stream>>>(h2, wp3, bp3, off);
    deform_gemm_bn_relu<64, 128, 16, 16, 16, 16, 1><<<1024, 256, 0, stream>>>(
        h2, off, wc3, g3, be3, m3, v3, h3);

    // Layer 4: deform 128->128, 16x16 -> 8x8, stride 2
    offset_conv<128, 16, 16, 8, 8, 2><<<1152, 256, 0, stream>>>(h3, wp4, bp4, off);
    deform_gemm_bn_relu<128, 128, 16, 16, 8, 8, 2><<<256, 256, 0, stream>>>(
        h3, off, wc4, g4, be4, m4, v4, h4);

    // Pool + FC
    pool_fc<<<256, 128, 0, stream>>>(h4, wcls, bcls, out);
}

// Round 2
// 955.139 us; speedup vs baseline: 1.7838x; 1.7838x over previous
//
#include <hip/hip_runtime.h>
#include <math.h>

#define BN_EPS 1e-5f

typedef __attribute__((ext_vector_type(8))) short short8;
typedef __attribute__((ext_vector_type(4))) float f32x4;

__device__ inline unsigned short f2bf(float f) {
    unsigned int u = __builtin_bit_cast(unsigned int, f);
    return (unsigned short)((u + 0x7FFFu + ((u >> 16) & 1u)) >> 16);
}

// ---------------- conv 3x3 stride1 pad1 + bias + BN + ReLU (layer 1) ----------------
template<int C, int O, int H, int W>
__global__ __launch_bounds__(256)
void conv3s1_bn_relu(const float* __restrict__ x, const float* __restrict__ w,
                     const float* __restrict__ bias,
                     const float* __restrict__ g, const float* __restrict__ be,
                     const float* __restrict__ m, const float* __restrict__ v,
                     float* __restrict__ out)
{
    int idx = blockIdx.x * 256 + threadIdx.x;
    int j = idx % W;
    int i = (idx / W) % H;
    int o = (idx / (W * H)) % O;
    int b = idx / (W * H * O);
    float acc = bias[o];
    for (int kh = 0; kh < 3; ++kh) {
        int ih = i - 1 + kh;
        if (ih < 0 || ih >= H) continue;
        for (int kw = 0; kw < 3; ++kw) {
            int iw = j - 1 + kw;
            if (iw < 0 || iw >= W) continue;
            const float* xq = x + ((size_t)b * C * H + ih) * W + iw;
            const float* wq = w + o * C * 9 + kh * 3 + kw;
            #pragma unroll
            for (int c = 0; c < C; ++c)
                acc = fmaf(xq[(size_t)c * H * W], wq[c * 9], acc);
        }
    }
    float sc = g[o] * rsqrtf(v[o] + BN_EPS);
    float sh = be[o] - m[o] * sc;
    out[idx] = fmaxf(fmaf(acc, sc, sh), 0.f);
}

// ---------------- weight convert: f32 (OREAL,K) -> bf16 (OPAD,K), zero pad rows ----------------
__global__ __launch_bounds__(256)
void cvt_w(const float* __restrict__ src, unsigned short* __restrict__ dst,
           int OREAL, int total, int K)
{
    int idx = blockIdx.x * 256 + threadIdx.x;
    if (idx >= total) return;
    int o = idx / K;
    dst[idx] = (o < OREAL) ? f2bf(src[idx]) : (unsigned short)0;
}

// ---------------- fused (deform-)conv as MFMA GEMM ----------------
// out[p][o] = sum_k B[p][k] * wgt[o][k], K = C*9, k = c*9 + n.
// DEF: B = bilinear deformable samples (table in LDS). !DEF: regular 3x3 taps.
// Per block: 16 pixels, 4 waves split K (interleaved k-steps), LDS atomic reduce.
// MFMA orientation: A-frag = weights (m=o), B-frag = pixels (n=pixel) ->
//   D[o][pixel]: lane holds o = t*16 + quad*4 + reg, pixel = lane&15.
template<int C, int OREAL, int OPAD, int H, int W, int OH, int OW, int S, bool DEF, bool BN>
__global__ __launch_bounds__(256)
void fused_conv_mfma(const float* __restrict__ x, const float* __restrict__ off,
                     const unsigned short* __restrict__ wq,
                     const float* __restrict__ q0, const float* __restrict__ q1,
                     const float* __restrict__ q2, const float* __restrict__ q3,
                     float* __restrict__ out)
{
    constexpr int K = C * 9;
    constexpr int NSTEP = K / 32;
    constexpr int OT = OPAD / 16;
    constexpr int HW = H * W;
    constexpr int OHW = OH * OW;
    constexpr int Hp = H + 2, Wp = W + 2;

    __shared__ short4 tbl_i[16][9];
    __shared__ float4 tbl_w[16][9];
    __shared__ short  tbl_r[16][9];
    __shared__ int    basearr[16];
    __shared__ float  red[OPAD * 16];

    const int tid = threadIdx.x;
    const int p0pix = blockIdx.x * 16;

    for (int e = tid; e < OPAD * 16; e += 256) red[e] = 0.f;
    if (tid < 16) {
        int p = p0pix + tid;
        basearr[tid] = (p / OHW) * (C * HW);
    }
    if (tid < 144) {
        int lp = tid / 9, n = tid % 9;
        int p = p0pix + lp;
        int b = p / OHW;
        int rem = p % OHW;
        int i = rem / OW, j = rem % OW;
        if (DEF) {
            float ox = off[((size_t)(b * 18 + n) * OH + i) * OW + j];
            float oy = off[((size_t)(b * 18 + 9 + n) * OH + i) * OW + j];
            float px = (float)(i * S + (n / 3)) + ox;   // 1 + i*S + (n/3 - 1)
            float py = (float)(j * S + (n % 3)) + oy;
            int qx0 = (int)floorf(px);
            int qy0 = (int)floorf(py);
            int x0 = min(max(qx0, 0), Hp - 1);
            int x1 = min(max(qx0 + 1, 0), Hp - 1);
            int y0 = min(max(qy0, 0), Wp - 1);
            int y1 = min(max(qy0 + 1, 0), Wp - 1);
            float pxc = fminf(fmaxf(px, 0.f), (float)(Hp - 1));
            float pyc = fminf(fmaxf(py, 0.f), (float)(Wp - 1));
            float gx0 = 1.f + ((float)x0 - pxc);
            float gx1 = 1.f - ((float)x1 - pxc);
            float gy0 = 1.f + ((float)y0 - pyc);
            float gy1 = 1.f - ((float)y1 - pyc);
            int u0 = x0 - 1, u1 = x1 - 1, v0 = y0 - 1, v1 = y1 - 1;
            short4 ti;
            ti.x = (u0 >= 0 && u0 < H && v0 >= 0 && v0 < W) ? (short)(u0 * W + v0) : (short)-1;
            ti.y = (u1 >= 0 && u1 < H && v1 >= 0 && v1 < W) ? (short)(u1 * W + v1) : (short)-1;
            ti.z = (u0 >= 0 && u0 < H && v1 >= 0 && v1 < W) ? (short)(u0 * W + v1) : (short)-1;
            ti.w = (u1 >= 0 && u1 < H && v0 >= 0 && v0 < W) ? (short)(u1 * W + v0) : (short)-1;
            tbl_i[lp][n] = ti;
            tbl_w[lp][n] = make_float4(gx0 * gy0, gx1 * gy1, gx0 * gy1, gx1 * gy0);
        } else {
            int u = i * S - 1 + (n / 3);
            int v = j * S - 1 + (n % 3);
            tbl_r[lp][n] = (u >= 0 && u < H && v >= 0 && v < W) ? (short)(u * W + v) : (short)-1;
        }
    }
    __syncthreads();

    const int wid = tid >> 6;
    const int lane = tid & 63;
    const int quad = lane >> 4;
    const int m16 = lane & 15;
    const float* xb = x + basearr[m16];   // pixel base for this lane's B-column

    f32x4 acc[OT];
    #pragma unroll
    for (int t = 0; t < OT; ++t) acc[t] = (f32x4){0.f, 0.f, 0.f, 0.f};

    for (int s = wid; s < NSTEP; s += 4) {
        const int kb = s * 32 + quad * 8;
        short8 bfrag;
        #pragma unroll
        for (int jj = 0; jj < 8; ++jj) {
            int k = kb + jj;
            int c = k / 9;
            int n = k - c * 9;
            const float* plane = xb + c * HW;
            float val;
            if (DEF) {
                short4 ti = tbl_i[m16][n];
                float4 tw = tbl_w[m16][n];
                val = 0.f;
                if (ti.x >= 0) val = fmaf(tw.x, plane[ti.x], val);
                if (ti.y >= 0) val = fmaf(tw.y, plane[ti.y], val);
                if (ti.z >= 0) val = fmaf(tw.z, plane[ti.z], val);
                if (ti.w >= 0) val = fmaf(tw.w, plane[ti.w], val);
            } else {
                short t0 = tbl_r[m16][n];
                val = (t0 >= 0) ? plane[t0] : 0.f;
            }
            bfrag[jj] = (short)f2bf(val);
        }
        #pragma unroll
        for (int t = 0; t < OT; ++t) {
            short8 afrag;
            __builtin_memcpy(&afrag, wq + (size_t)(t * 16 + m16) * K + kb, 16);
            acc[t] = __builtin_amdgcn_mfma_f32_16x16x32_bf16(afrag, bfrag, acc[t], 0, 0, 0);
        }
    }

    // reduce partial K-sums across waves
    #pragma unroll
    for (int t = 0; t < OT; ++t) {
        int o = t * 16 + quad * 4;
        #pragma unroll
        for (int r = 0; r < 4; ++r)
            atomicAdd(&red[(o + r) * 16 + m16], acc[t][r]);
    }
    __syncthreads();

    // epilogue: BN+ReLU (deform) or +bias (offset conv); coalesced stores
    for (int e = tid; e < OREAL * 16; e += 256) {
        int o = e >> 4, pix = e & 15;
        int p = p0pix + pix;
        int b = p / OHW, rem = p % OHW;
        float vv = red[e];
        float res;
        if (BN) {
            float sc = q0[o] * rsqrtf(q3[o] + BN_EPS);
            float sh = q1[o] - q2[o] * sc;
            res = fmaxf(fmaf(vv, sc, sh), 0.f);
        } else {
            res = vv + q0[o];
        }
        out[((size_t)(b * OREAL + o)) * OHW + rem] = res;
    }
}

// ---------------- global avg pool (8x8) + FC 128->100 ----------------
__global__ __launch_bounds__(128)
void pool_fc(const float* __restrict__ h4, const float* __restrict__ wcls,
             const float* __restrict__ bcls, float* __restrict__ out)
{
    __shared__ float pool[128];
    int b = blockIdx.x;
    int tid = threadIdx.x;
    const float* src = h4 + ((size_t)b * 128 + tid) * 64;
    float s = 0.f;
    #pragma unroll
    for (int t = 0; t < 64; ++t) s += src[t];
    pool[tid] = s * (1.f / 64.f);
    __syncthreads();
    if (tid < 100) {
        float acc = bcls[tid];
        const float* wr = wcls + tid * 128;
        #pragma unroll
        for (int c = 0; c < 128; ++c) acc = fmaf(pool[c], wr[c], acc);
        out[(size_t)b * 100 + tid] = acc;
    }
}

extern "C" void kernel_launch(void* const* d_in, const int* in_sizes, int n_in,
                              void* d_out, int out_size, void* d_ws, size_t ws_size,
                              hipStream_t stream)
{
    const float* x    = (const float*)d_in[0];
    const float* w1   = (const float*)d_in[1];
    const float* b1   = (const float*)d_in[2];
    const float* g1   = (const float*)d_in[3];
    const float* be1  = (const float*)d_in[4];
    const float* m1   = (const float*)d_in[5];
    const float* v1   = (const float*)d_in[6];
    const float* wp2  = (const float*)d_in[7];
    const float* bp2  = (const float*)d_in[8];
    const float* wc2  = (const float*)d_in[9];
    const float* g2   = (const float*)d_in[10];
    const float* be2  = (const float*)d_in[11];
    const float* m2   = (const float*)d_in[12];
    const float* v2   = (const float*)d_in[13];
    const float* wp3  = (const float*)d_in[14];
    const float* bp3  = (const float*)d_in[15];
    const float* wc3  = (const float*)d_in[16];
    const float* g3   = (const float*)d_in[17];
    const float* be3  = (const float*)d_in[18];
    const float* m3   = (const float*)d_in[19];
    const float* v3   = (const float*)d_in[20];
    const float* wp4  = (const float*)d_in[21];
    const float* bp4  = (const float*)d_in[22];
    const float* wc4  = (const float*)d_in[23];
    const float* g4   = (const float*)d_in[24];
    const float* be4  = (const float*)d_in[25];
    const float* m4   = (const float*)d_in[26];
    const float* v4   = (const float*)d_in[27];
    const float* wcls = (const float*)d_in[28];
    const float* bcls = (const float*)d_in[29];
    float* out = (float*)d_out;

    float* ws  = (float*)d_ws;
    float* h1  = ws;                  // 256*32*32*32 = 8,388,608 f32
    float* off = h1 + 8388608;        // max 256*18*16*16 = 1,179,648 f32 (reused)
    float* h2  = off + 1179648;       // 256*64*16*16 = 4,194,304
    float* h3  = h2 + 4194304;        // 256*128*16*16 = 8,388,608
    float* h4  = h3 + 8388608;        // 256*128*8*8 = 2,097,152
    unsigned short* wb = (unsigned short*)(h4 + 2097152);
    unsigned short* wc2b = wb;                 //  64*288  = 18432
    unsigned short* wc3b = wc2b + 18432;       // 128*576  = 73728
    unsigned short* wc4b = wc3b + 73728;       // 128*1152 = 147456
    unsigned short* wp2b = wc4b + 147456;      //  32*288  = 9216
    unsigned short* wp3b = wp2b + 9216;        //  32*576  = 18432
    unsigned short* wp4b = wp3b + 18432;       //  32*1152 = 36864
    (void)ws_size; (void)in_sizes; (void)n_in; (void)out_size;

    // weight conversions (f32 -> bf16, pad offset-conv O to 32)
    cvt_w<<<(64 * 288 + 255) / 256, 256, 0, stream>>>(wc2, wc2b, 64, 64 * 288, 288);
    cvt_w<<<(128 * 576 + 255) / 256, 256, 0, stream>>>(wc3, wc3b, 128, 128 * 576, 576);
    cvt_w<<<(128 * 1152 + 255) / 256, 256, 0, stream>>>(wc4, wc4b, 128, 128 * 1152, 1152);
    cvt_w<<<(32 * 288 + 255) / 256, 256, 0, stream>>>(wp2, wp2b, 18, 32 * 288, 288);
    cvt_w<<<(32 * 576 + 255) / 256, 256, 0, stream>>>(wp3, wp3b, 18, 32 * 576, 576);
    cvt_w<<<(32 * 1152 + 255) / 256, 256, 0, stream>>>(wp4, wp4b, 18, 32 * 1152, 1152);

    // Layer 1: conv 3->32, 32x32
    conv3s1_bn_relu<3, 32, 32, 32><<<32768, 256, 0, stream>>>(
        x, w1, b1, g1, be1, m1, v1, h1);

    // Layer 2: 32x32 -> 16x16, stride 2, C=32 -> O=64
    fused_conv_mfma<32, 18, 32, 32, 32, 16, 16, 2, false, false><<<4096, 256, 0, stream>>>(
        h1, nullptr, wp2b, bp2, nullptr, nullptr, nullptr, off);
    fused_conv_mfma<32, 64, 64, 32, 32, 16, 16, 2, true, true><<<4096, 256, 0, stream>>>(
        h1, off, wc2b, g2, be2, m2, v2, h2);

    // Layer 3: 16x16 -> 16x16, stride 1, C=64 -> O=128
    fused_conv_mfma<64, 18, 32, 16, 16, 16, 16, 1, false, false><<<4096, 256, 0, stream>>>(
        h2, nullptr, wp3b, bp3, nullptr, nullptr, nullptr, off);
    fused_conv_mfma<64, 128, 128, 16, 16, 16, 16, 1, true, true><<<4096, 256, 0, stream>>>(
        h2, off, wc3b, g3, be3, m3, v3, h3);

    // Layer 4: 16x16 -> 8x8, stride 2, C=128 -> O=128
    fused_conv_mfma<128, 18, 32, 16, 16, 8, 8, 2, false, false><<<1024, 256, 0, stream>>>(
        h3, nullptr, wp4b, bp4, nullptr, nullptr, nullptr, off);
    fused_conv_mfma<128, 128, 128, 16, 16, 8, 8, 2, true, true><<<1024, 256, 0, stream>>>(
        h3, off, wc4b, g4, be4, m4, v4, h4);

    // Pool + FC
    pool_fc<<<256, 128, 0, stream>>>(h4, wcls, bcls, out);
}

// Round 3
// 469.422 us; speedup vs baseline: 3.6296x; 2.0347x over previous
//
#include <hip/hip_runtime.h>
#include <math.h>

#define BN_EPS 1e-5f

typedef __attribute__((ext_vector_type(4))) float f4;
typedef __attribute__((ext_vector_type(4))) int i4v;
typedef __attribute__((ext_vector_type(8))) short short8;
typedef __attribute__((ext_vector_type(4))) float f32x4;

__device__ inline unsigned short f2bf(float f) {
    unsigned int u = __builtin_bit_cast(unsigned int, f);
    return (unsigned short)((u + 0x7FFFu + ((u >> 16) & 1u)) >> 16);
}

// ---------------- fused weight conversion: all 7 weight tensors ----------------
// dst[o][k] bf16 with k = n*C + c permutation of src[o][c][3][3]; zero-pads
// rows o >= oreal and k >= 9*C (conv1 pads K 27->32).
struct CvtSeg { const float* src; unsigned short* dst; int oreal, c, kpad, end; };
struct CvtArgs { CvtSeg s[7]; };

__global__ __launch_bounds__(256)
void cvt_all(CvtArgs a)
{
    int idx = blockIdx.x * 256 + threadIdx.x;
    int base = 0;
    #pragma unroll
    for (int i = 0; i < 7; ++i) {
        if (idx < a.s[i].end) {
            int local = idx - base;
            int kpad = a.s[i].kpad, c = a.s[i].c;
            int o = local / kpad, k = local - o * kpad;
            unsigned short val = 0;
            if (o < a.s[i].oreal && k < 9 * c) {
                int n = k / c, cc = k - n * c;
                val = f2bf(a.s[i].src[(o * c + cc) * 9 + n]);
            }
            a.s[i].dst[local] = val;
            return;
        }
        base = a.s[i].end;
    }
}

// ---------------- layer 1: conv 3->32 as MFMA, NCHW in -> NHWC out ----------------
__global__ __launch_bounds__(256)
void conv1_mfma(const float* __restrict__ x, const unsigned short* __restrict__ wq,
                const float* __restrict__ bias, const float* __restrict__ g,
                const float* __restrict__ be, const float* __restrict__ m,
                const float* __restrict__ v, float* __restrict__ out)
{
    // H=W=32, C=3, O=32, K padded 27->32, k = n*3 + c
    __shared__ int   tbl_o[64][9];
    __shared__ float tbl_s[64][9];
    __shared__ float scb[32], shb[32];
    const int tid = threadIdx.x;
    const int p0 = blockIdx.x * 64;
    if (tid < 32) {
        float sc = g[tid] * rsqrtf(v[tid] + BN_EPS);
        scb[tid] = sc;
        shb[tid] = be[tid] - m[tid] * sc + bias[tid] * sc;  // fold conv bias into BN
    }
    for (int e = tid; e < 64 * 9; e += 256) {
        int lp = e / 9, n = e % 9;
        int p = p0 + lp;
        int rem = p & 1023;
        int i = rem >> 5, j = rem & 31;
        int u = i - 1 + n / 3, vv = j - 1 + n % 3;
        bool ok = (u >= 0 && u < 32 && vv >= 0 && vv < 32);
        tbl_o[lp][n] = ok ? (u * 32 + vv) : 0;
        tbl_s[lp][n] = ok ? 1.f : 0.f;
    }
    __syncthreads();
    const int wid = tid >> 6, lane = tid & 63, quad = lane >> 4, m16 = lane & 15;
    const int pix = wid * 16 + m16;
    const int p = p0 + pix;
    const float* ib = x + (size_t)(p >> 10) * 3072;
    const int kb = quad * 8;
    short8 bfrag;
    #pragma unroll
    for (int j = 0; j < 8; ++j) {
        int k = kb + j;
        float val = 0.f;
        if (k < 27) {
            int n = k / 3, c = k - n * 3;
            val = tbl_s[pix][n] * ib[tbl_o[pix][n] + c * 1024];
        }
        bfrag[j] = (short)f2bf(val);
    }
    f32x4 acc[2] = {{0.f,0.f,0.f,0.f},{0.f,0.f,0.f,0.f}};
    #pragma unroll
    for (int t = 0; t < 2; ++t) {
        short8 afrag;
        __builtin_memcpy(&afrag, wq + (t * 16 + m16) * 32 + kb, 16);
        acc[t] = __builtin_amdgcn_mfma_f32_16x16x32_bf16(afrag, bfrag, acc[t], 0, 0, 0);
    }
    #pragma unroll
    for (int t = 0; t < 2; ++t) {
        int o = t * 16 + quad * 4;
        f4 r;
        #pragma unroll
        for (int rr = 0; rr < 4; ++rr)
            r[rr] = fmaxf(fmaf(acc[t][rr], scb[o + rr], shb[o + rr]), 0.f);
        *(f4*)(out + (size_t)p * 32 + o) = r;
    }
}

// ---------------- unified offset-conv / deform-conv MFMA, NHWC in ----------------
// out[p][o] = sum_k B[p][k] * wq[o][k], k = n*C + c. B gathered on the fly:
// DEF: 4 bilinear taps (channel-contiguous float4 pairs); !DEF: single tap.
// Each wave owns 16 pixels and the full K range; no cross-wave reduce.
template<int C, int OREAL, int OPAD, int H, int W, int OH, int OW, int S,
         int NPIXB, bool DEF, bool BN>
__global__ __launch_bounds__(NPIXB * 4)
void conv_mfma(const float* __restrict__ x, const float* __restrict__ off,
               const unsigned short* __restrict__ wq,
               const float* __restrict__ q0, const float* __restrict__ q1,
               const float* __restrict__ q2, const float* __restrict__ q3,
               float* __restrict__ out)
{
    constexpr int K = C * 9;
    constexpr int NSTEP = K / 32;
    constexpr int OT = OPAD / 16;
    constexpr int HW = H * W;
    constexpr int OHW = OH * OW;
    constexpr int Hp = H + 2, Wp = W + 2;
    constexpr int THREADS = NPIXB * 4;

    __shared__ i4v   tbl_i[DEF ? NPIXB : 1][9];
    __shared__ f4    tbl_w[DEF ? NPIXB : 1][9];
    __shared__ int   tbl_o[DEF ? 1 : NPIXB][9];
    __shared__ float tbl_s[DEF ? 1 : NPIXB][9];
    __shared__ int   imgb[NPIXB];
    __shared__ float scb[BN ? OPAD : 1];
    __shared__ float shb[BN ? OPAD : 1];

    const int tid = threadIdx.x;
    const int p0 = blockIdx.x * NPIXB;

    if (tid < NPIXB) imgb[tid] = ((p0 + tid) / OHW) * (C * HW);
    if (BN) {
        for (int o = tid; o < OREAL; o += THREADS) {
            float sc = q0[o] * rsqrtf(q3[o] + BN_EPS);
            scb[o] = sc;
            shb[o] = q1[o] - q2[o] * sc;
        }
    }
    for (int e = tid; e < NPIXB * 9; e += THREADS) {
        int lp = e / 9, n = e % 9;
        int p = p0 + lp;
        int b = p / OHW, rem = p % OHW;
        int i = rem / OW, j = rem % OW;
        if constexpr (DEF) {
            float ox = off[((size_t)(b * 18 + n) * OH + i) * OW + j];
            float oy = off[((size_t)(b * 18 + 9 + n) * OH + i) * OW + j];
            float px = (float)(i * S + n / 3) + ox;   // 1 + i*S + (n/3 - 1)
            float py = (float)(j * S + n % 3) + oy;
            int qx0 = (int)floorf(px), qy0 = (int)floorf(py);
            int x0 = min(max(qx0, 0), Hp - 1), x1 = min(max(qx0 + 1, 0), Hp - 1);
            int y0 = min(max(qy0, 0), Wp - 1), y1 = min(max(qy0 + 1, 0), Wp - 1);
            float pxc = fminf(fmaxf(px, 0.f), (float)(Hp - 1));
            float pyc = fminf(fmaxf(py, 0.f), (float)(Wp - 1));
            float gx0 = 1.f + ((float)x0 - pxc), gx1 = 1.f - ((float)x1 - pxc);
            float gy0 = 1.f + ((float)y0 - pyc), gy1 = 1.f - ((float)y1 - pyc);
            int u0 = x0 - 1, u1 = x1 - 1, v0 = y0 - 1, v1 = y1 - 1;
            bool k0 = (u0 >= 0 && u0 < H && v0 >= 0 && v0 < W);
            bool k1 = (u1 >= 0 && u1 < H && v1 >= 0 && v1 < W);
            bool k2 = (u0 >= 0 && u0 < H && v1 >= 0 && v1 < W);
            bool k3 = (u1 >= 0 && u1 < H && v0 >= 0 && v0 < W);
            i4v ti; f4 tw;
            ti[0] = k0 ? (u0 * W + v0) * C : 0;  tw[0] = k0 ? gx0 * gy0 : 0.f;
            ti[1] = k1 ? (u1 * W + v1) * C : 0;  tw[1] = k1 ? gx1 * gy1 : 0.f;
            ti[2] = k2 ? (u0 * W + v1) * C : 0;  tw[2] = k2 ? gx0 * gy1 : 0.f;
            ti[3] = k3 ? (u1 * W + v0) * C : 0;  tw[3] = k3 ? gx1 * gy0 : 0.f;
            tbl_i[lp][n] = ti;
            tbl_w[lp][n] = tw;
        } else {
            int u = i * S - 1 + n / 3, vv = j * S - 1 + n % 3;
            bool ok = (u >= 0 && u < H && vv >= 0 && vv < W);
            tbl_o[lp][n] = ok ? (u * W + vv) * C : 0;
            tbl_s[lp][n] = ok ? 1.f : 0.f;
        }
    }
    __syncthreads();

    const int wid = tid >> 6, lane = tid & 63, quad = lane >> 4, m16 = lane & 15;
    const int pix = wid * 16 + m16;
    const float* ib = x + imgb[pix];

    f32x4 acc[OT];
    #pragma unroll
    for (int t = 0; t < OT; ++t) acc[t] = (f32x4){0.f, 0.f, 0.f, 0.f};

    #pragma unroll 2
    for (int s = 0; s < NSTEP; ++s) {
        const int kb = s * 32 + quad * 8;
        const int n = kb / C, c0 = kb % C;
        f4 lo, hi;
        if constexpr (DEF) {
            i4v ti = tbl_i[pix][n];
            f4  tw = tbl_w[pix][n];
            const float* pa = ib + ti[0] + c0;
            const float* pb = ib + ti[1] + c0;
            const float* pc = ib + ti[2] + c0;
            const float* pd = ib + ti[3] + c0;
            f4 a0 = *(const f4*)pa, a1 = *(const f4*)(pa + 4);
            f4 b0 = *(const f4*)pb, b1 = *(const f4*)(pb + 4);
            f4 c0v = *(const f4*)pc, c1 = *(const f4*)(pc + 4);
            f4 d0 = *(const f4*)pd, d1 = *(const f4*)(pd + 4);
            lo = a0 * tw[0] + b0 * tw[1] + c0v * tw[2] + d0 * tw[3];
            hi = a1 * tw[0] + b1 * tw[1] + c1 * tw[2] + d1 * tw[3];
        } else {
            const float* pa = ib + tbl_o[pix][n] + c0;
            float wv = tbl_s[pix][n];
            lo = *(const f4*)pa * wv;
            hi = *(const f4*)(pa + 4) * wv;
        }
        short8 bfrag;
        #pragma unroll
        for (int j = 0; j < 4; ++j) bfrag[j] = (short)f2bf(lo[j]);
        #pragma unroll
        for (int j = 0; j < 4; ++j) bfrag[4 + j] = (short)f2bf(hi[j]);
        #pragma unroll
        for (int t = 0; t < OT; ++t) {
            short8 afrag;
            __builtin_memcpy(&afrag, wq + (size_t)(t * 16 + m16) * K + kb, 16);
            acc[t] = __builtin_amdgcn_mfma_f32_16x16x32_bf16(afrag, bfrag, acc[t], 0, 0, 0);
        }
    }

    if constexpr (BN) {
        // deform output: NHWC float4 stores, BN+ReLU
        const int p = p0 + pix;
        #pragma unroll
        for (int t = 0; t < OT; ++t) {
            int o = t * 16 + quad * 4;
            f4 r;
            #pragma unroll
            for (int rr = 0; rr < 4; ++rr)
                r[rr] = fmaxf(fmaf(acc[t][rr], scb[o + rr], shb[o + rr]), 0.f);
            *(f4*)(out + (size_t)p * OPAD + o) = r;
        }
    } else {
        // offset-conv output: NCHW (b,18,OH,OW) + bias
        const int p = p0 + pix;
        int b = p / OHW, rem = p % OHW;
        int i = rem / OW, j = rem % OW;
        #pragma unroll
        for (int t = 0; t < OT; ++t) {
            #pragma unroll
            for (int rr = 0; rr < 4; ++rr) {
                int o = t * 16 + quad * 4 + rr;
                if (o < OREAL)
                    out[((size_t)(b * 18 + o) * OH + i) * OW + j] = acc[t][rr] + q0[o];
            }
        }
    }
}

// ---------------- global avg pool (8x8, NHWC) + FC 128->100 ----------------
__global__ __launch_bounds__(128)
void pool_fc(const float* __restrict__ h4, const float* __restrict__ wcls,
             const float* __restrict__ bcls, float* __restrict__ out)
{
    __shared__ float pool[128];
    int b = blockIdx.x;
    int tid = threadIdx.x;   // one per channel
    const float* src = h4 + (size_t)b * 8192;
    float s = 0.f;
    #pragma unroll
    for (int t = 0; t < 64; ++t) s += src[t * 128 + tid];
    pool[tid] = s * (1.f / 64.f);
    __syncthreads();
    if (tid < 100) {
        float acc = bcls[tid];
        const float* wr = wcls + tid * 128;
        #pragma unroll
        for (int c = 0; c < 128; ++c) acc = fmaf(pool[c], wr[c], acc);
        out[(size_t)b * 100 + tid] = acc;
    }
}

extern "C" void kernel_launch(void* const* d_in, const int* in_sizes, int n_in,
                              void* d_out, int out_size, void* d_ws, size_t ws_size,
                              hipStream_t stream)
{
    const float* x    = (const float*)d_in[0];
    const float* w1   = (const float*)d_in[1];
    const float* b1   = (const float*)d_in[2];
    const float* g1   = (const float*)d_in[3];
    const float* be1  = (const float*)d_in[4];
    const float* m1   = (const float*)d_in[5];
    const float* v1   = (const float*)d_in[6];
    const float* wp2  = (const float*)d_in[7];
    const float* bp2  = (const float*)d_in[8];
    const float* wc2  = (const float*)d_in[9];
    const float* g2   = (const float*)d_in[10];
    const float* be2  = (const float*)d_in[11];
    const float* m2   = (const float*)d_in[12];
    const float* v2   = (const float*)d_in[13];
    const float* wp3  = (const float*)d_in[14];
    const float* bp3  = (const float*)d_in[15];
    const float* wc3  = (const float*)d_in[16];
    const float* g3   = (const float*)d_in[17];
    const float* be3  = (const float*)d_in[18];
    const float* m3   = (const float*)d_in[19];
    const float* v3   = (const float*)d_in[20];
    const float* wp4  = (const float*)d_in[21];
    const float* bp4  = (const float*)d_in[22];
    const float* wc4  = (const float*)d_in[23];
    const float* g4   = (const float*)d_in[24];
    const float* be4  = (const float*)d_in[25];
    const float* m4   = (const float*)d_in[26];
    const float* v4   = (const float*)d_in[27];
    const float* wcls = (const float*)d_in[28];
    const float* bcls = (const float*)d_in[29];
    float* out = (float*)d_out;

    float* ws  = (float*)d_ws;
    float* h1  = ws;                  // NHWC 256*32*32*32 = 8,388,608 f32
    float* off = h1 + 8388608;        // NCHW max 256*18*16*16 = 1,179,648 (reused)
    float* h2  = off + 1179648;       // NHWC 256*16*16*64 = 4,194,304
    float* h3  = h2 + 4194304;        // NHWC 256*16*16*128 = 8,388,608
    float* h4  = h3 + 8388608;        // NHWC 256*8*8*128 = 2,097,152
    unsigned short* wc2b = (unsigned short*)(h4 + 2097152);  // 64*288
    unsigned short* wc3b = wc2b + 18432;       // 128*576
    unsigned short* wc4b = wc3b + 73728;       // 128*1152
    unsigned short* wp2b = wc4b + 147456;      // 32*288
    unsigned short* wp3b = wp2b + 9216;        // 32*576
    unsigned short* wp4b = wp3b + 18432;       // 32*1152
    unsigned short* wq1  = wp4b + 36864;       // 32*32
    (void)ws_size; (void)in_sizes; (void)n_in; (void)out_size;

    // single fused weight-conversion kernel (k = n*C + c reordering, bf16)
    CvtArgs ca;
    ca.s[0] = { wc2, wc2b, 64, 32, 288, 18432 };
    ca.s[1] = { wc3, wc3b, 128, 64, 576, 92160 };
    ca.s[2] = { wc4, wc4b, 128, 128, 1152, 239616 };
    ca.s[3] = { wp2, wp2b, 18, 32, 288, 248832 };
    ca.s[4] = { wp3, wp3b, 18, 64, 576, 267264 };
    ca.s[5] = { wp4, wp4b, 18, 128, 1152, 304128 };
    ca.s[6] = { w1, wq1, 32, 3, 32, 305152 };
    cvt_all<<<1192, 256, 0, stream>>>(ca);

    // Layer 1: conv 3->32 (MFMA), NCHW in, NHWC out
    conv1_mfma<<<4096, 256, 0, stream>>>(x, wq1, b1, g1, be1, m1, v1, h1);

    // Layer 2: 32x32 -> 16x16, stride 2, C=32 -> O=64
    conv_mfma<32, 18, 32, 32, 32, 16, 16, 2, 64, false, false><<<1024, 256, 0, stream>>>(
        h1, nullptr, wp2b, bp2, nullptr, nullptr, nullptr, off);
    conv_mfma<32, 64, 64, 32, 32, 16, 16, 2, 64, true, true><<<1024, 256, 0, stream>>>(
        h1, off, wc2b, g2, be2, m2, v2, h2);

    // Layer 3: 16x16 -> 16x16, stride 1, C=64 -> O=128
    conv_mfma<64, 18, 32, 16, 16, 16, 16, 1, 64, false, false><<<1024, 256, 0, stream>>>(
        h2, nullptr, wp3b, bp3, nullptr, nullptr, nullptr, off);
    conv_mfma<64, 128, 128, 16, 16, 16, 16, 1, 64, true, true><<<1024, 256, 0, stream>>>(
        h2, off, wc3b, g3, be3, m3, v3, h3);

    // Layer 4: 16x16 -> 8x8, stride 2, C=128 -> O=128
    conv_mfma<128, 18, 32, 16, 16, 8, 8, 2, 32, false, false><<<512, 128, 0, stream>>>(
        h3, nullptr, wp4b, bp4, nullptr, nullptr, nullptr, off);
    conv_mfma<128, 128, 128, 16, 16, 8, 8, 2, 32, true, true><<<512, 128, 0, stream>>>(
        h3, off, wc4b, g4, be4, m4, v4, h4);

    // Pool + FC
    pool_fc<<<256, 128, 0, stream>>>(h4, wcls, bcls, out);
}

// Round 4
// 319.395 us; speedup vs baseline: 5.3345x; 1.4697x over previous
//
#include <hip/hip_runtime.h>
#include <math.h>

#define BN_EPS 1e-5f

typedef __attribute__((ext_vector_type(4))) float f4;
typedef __attribute__((ext_vector_type(4))) int i4v;
typedef __attribute__((ext_vector_type(8))) short short8;
typedef __attribute__((ext_vector_type(4))) float f32x4;

__device__ inline unsigned short f2bf(float f) {
    unsigned int u = __builtin_bit_cast(unsigned int, f);
    return (unsigned short)((u + 0x7FFFu + ((u >> 16) & 1u)) >> 16);
}

// ---------------- fused weight conversion: all 7 weight tensors ----------------
// dst[o][k] bf16 with k = n*C + c permutation of src[o][c][3][3]; zero-pads
// rows o >= oreal and k >= 9*C (conv1 pads K 27->32).
struct CvtSeg { const float* src; unsigned short* dst; int oreal, c, kpad, end; };
struct CvtArgs { CvtSeg s[7]; };

__global__ __launch_bounds__(256)
void cvt_all(CvtArgs a)
{
    int idx = blockIdx.x * 256 + threadIdx.x;
    int base = 0;
    #pragma unroll
    for (int i = 0; i < 7; ++i) {
        if (idx < a.s[i].end) {
            int local = idx - base;
            int kpad = a.s[i].kpad, c = a.s[i].c;
            int o = local / kpad, k = local - o * kpad;
            unsigned short val = 0;
            if (o < a.s[i].oreal && k < 9 * c) {
                int n = k / c, cc = k - n * c;
                val = f2bf(a.s[i].src[(o * c + cc) * 9 + n]);
            }
            a.s[i].dst[local] = val;
            return;
        }
        base = a.s[i].end;
    }
}

// ---------------- layer 1: whole image in LDS + MFMA ----------------
// block = 1 image (1024 px), NCHW in (3x32x32), NHWC out (32ch)
__global__ __launch_bounds__(256)
void conv1_tile(const float* __restrict__ x, const unsigned short* __restrict__ wq,
                const float* __restrict__ bias, const float* __restrict__ g,
                const float* __restrict__ be, const float* __restrict__ m,
                const float* __restrict__ v, float* __restrict__ out)
{
    __shared__ __align__(16) float img[3072];
    __shared__ __align__(16) unsigned short wt[32 * 40];
    __shared__ float scb[32], shb[32];
    const int tid = threadIdx.x;
    const int b = blockIdx.x;
    if (tid < 32) {
        float sc = g[tid] * rsqrtf(v[tid] + BN_EPS);
        scb[tid] = sc;
        shb[tid] = be[tid] - m[tid] * sc + bias[tid] * sc;
    }
    *(ushort4*)&wt[(tid >> 3) * 40 + (tid & 7) * 4] =
        *(const ushort4*)(wq + (tid >> 3) * 32 + (tid & 7) * 4);
    const float* xb = x + (size_t)b * 3072;
    #pragma unroll
    for (int r = 0; r < 3; ++r) {
        int idx = r * 256 + tid;
        *(f4*)&img[idx * 4] = *(const f4*)(xb + idx * 4);
    }
    __syncthreads();
    const int wid = tid >> 6, lane = tid & 63, quad = lane >> 4, m16 = lane & 15;
    short8 af0 = *(const short8*)&wt[m16 * 40 + quad * 8];
    short8 af1 = *(const short8*)&wt[(16 + m16) * 40 + quad * 8];
    for (int it = 0; it < 16; ++it) {
        int pix = it * 64 + wid * 16 + m16;
        int i = pix >> 5, j = pix & 31;
        short8 bfrag;
        #pragma unroll
        for (int jj = 0; jj < 8; ++jj) {
            int k = quad * 8 + jj;
            float val = 0.f;
            if (k < 27) {
                int n = k / 3, c = k - n * 3;
                int u = i - 1 + n / 3, vv = j - 1 + n % 3;
                if (u >= 0 && u < 32 && vv >= 0 && vv < 32)
                    val = img[c * 1024 + u * 32 + vv];
            }
            bfrag[jj] = (short)f2bf(val);
        }
        f32x4 a0 = {0.f,0.f,0.f,0.f}, a1 = {0.f,0.f,0.f,0.f};
        a0 = __builtin_amdgcn_mfma_f32_16x16x32_bf16(af0, bfrag, a0, 0, 0, 0);
        a1 = __builtin_amdgcn_mfma_f32_16x16x32_bf16(af1, bfrag, a1, 0, 0, 0);
        float* op = out + ((size_t)b * 1024 + pix) * 32;
        f4 r0, r1;
        #pragma unroll
        for (int rr = 0; rr < 4; ++rr) {
            int o0 = quad * 4 + rr, o1 = 16 + quad * 4 + rr;
            r0[rr] = fmaxf(fmaf(a0[rr], scb[o0], shb[o0]), 0.f);
            r1[rr] = fmaxf(fmaf(a1[rr], scb[o1], shb[o1]), 0.f);
        }
        *(f4*)(op + quad * 4) = r0;
        *(f4*)(op + 16 + quad * 4) = r1;
    }
}

// ---------------- tiled (deform-)conv: LDS x_off gather + LDS-weight MFMA ----------------
// out[p][o] = sum_k B[p][k]*wq[o][k], k = n*C + c (NHWC input).
// Phase 1: bilinear table. Phase 2: cooperative coalesced gather -> LDS xoff (bf16).
// Phase 3: per-32k chunk, stage weights to LDS, MFMA from LDS.
template<int C, int OREAL, int OPAD, int H, int W, int OH, int OW, int S,
         int MTILE, int NU, bool DEF, bool BN>
__global__ __launch_bounds__(256)
void conv_tile(const float* __restrict__ x, const float* __restrict__ off,
               const unsigned short* __restrict__ wq,
               const float* __restrict__ q0, const float* __restrict__ q1,
               const float* __restrict__ q2, const float* __restrict__ q3,
               float* __restrict__ out)
{
    constexpr int K = C * 9;
    constexpr int G = MTILE / 16;       // pixel groups
    constexpr int WC = 4 / G;           // O-split wave groups
    constexpr int OT = OPAD / (16 * WC);
    constexpr int KPL = NU * C + 8;     // local xoff row (shorts), %8==0
    constexpr int GL = (C == 32) ? 8 : ((C == 64) ? 16 : 32);  // lanes per gather task
    constexpr int NGRP = 256 / GL;
    constexpr int HW = H * W;
    constexpr int OHW = OH * OW;
    constexpr int Hp = H + 2, Wp = W + 2;
    static_assert(C == GL * 4, "gather covers C");
    static_assert((NU * C) % 32 == 0 && 9 % NU == 0, "chunking");

    __shared__ __align__(16) unsigned short xoff[MTILE * KPL];
    __shared__ __align__(16) unsigned short wt[OPAD * 40];
    __shared__ int   imgb[MTILE];
    __shared__ i4v   tbl_i[DEF ? MTILE : 1][9];
    __shared__ f4    tbl_w[DEF ? MTILE : 1][9];
    __shared__ int   tbl_o[DEF ? 1 : MTILE][9];
    __shared__ float tbl_s[DEF ? 1 : MTILE][9];
    __shared__ float scb[BN ? OPAD : 1], shb[BN ? OPAD : 1];

    const int tid = threadIdx.x;
    const int p0 = blockIdx.x * MTILE;

    if (tid < MTILE) imgb[tid] = ((p0 + tid) / OHW) * (C * HW);
    if (BN) {
        for (int o = tid; o < OREAL; o += 256) {
            float sc = q0[o] * rsqrtf(q3[o] + BN_EPS);
            scb[o] = sc;
            shb[o] = q1[o] - q2[o] * sc;
        }
    }
    for (int e = tid; e < MTILE * 9; e += 256) {
        int lp = e / 9, n = e % 9;
        int p = p0 + lp;
        int b = p / OHW, rem = p % OHW;
        int i = rem / OW, j = rem % OW;
        if constexpr (DEF) {
            float ox = off[((size_t)(b * 18 + n) * OH + i) * OW + j];
            float oy = off[((size_t)(b * 18 + 9 + n) * OH + i) * OW + j];
            float px = (float)(i * S + n / 3) + ox;
            float py = (float)(j * S + n % 3) + oy;
            int qx0 = (int)floorf(px), qy0 = (int)floorf(py);
            int x0 = min(max(qx0, 0), Hp - 1), x1 = min(max(qx0 + 1, 0), Hp - 1);
            int y0 = min(max(qy0, 0), Wp - 1), y1 = min(max(qy0 + 1, 0), Wp - 1);
            float pxc = fminf(fmaxf(px, 0.f), (float)(Hp - 1));
            float pyc = fminf(fmaxf(py, 0.f), (float)(Wp - 1));
            float gx0 = 1.f + ((float)x0 - pxc), gx1 = 1.f - ((float)x1 - pxc);
            float gy0 = 1.f + ((float)y0 - pyc), gy1 = 1.f - ((float)y1 - pyc);
            int u0 = x0 - 1, u1 = x1 - 1, v0 = y0 - 1, v1 = y1 - 1;
            bool k0 = (u0 >= 0 && u0 < H && v0 >= 0 && v0 < W);
            bool k1 = (u1 >= 0 && u1 < H && v1 >= 0 && v1 < W);
            bool k2 = (u0 >= 0 && u0 < H && v1 >= 0 && v1 < W);
            bool k3 = (u1 >= 0 && u1 < H && v0 >= 0 && v0 < W);
            i4v ti; f4 tw;
            ti[0] = k0 ? (u0 * W + v0) * C : 0;  tw[0] = k0 ? gx0 * gy0 : 0.f;
            ti[1] = k1 ? (u1 * W + v1) * C : 0;  tw[1] = k1 ? gx1 * gy1 : 0.f;
            ti[2] = k2 ? (u0 * W + v1) * C : 0;  tw[2] = k2 ? gx0 * gy1 : 0.f;
            ti[3] = k3 ? (u1 * W + v0) * C : 0;  tw[3] = k3 ? gx1 * gy0 : 0.f;
            tbl_i[lp][n] = ti;
            tbl_w[lp][n] = tw;
        } else {
            int u = i * S - 1 + n / 3, vv = j * S - 1 + n % 3;
            bool ok = (u >= 0 && u < H && vv >= 0 && vv < W);
            tbl_o[lp][n] = ok ? (u * W + vv) * C : 0;
            tbl_s[lp][n] = ok ? 1.f : 0.f;
        }
    }
    __syncthreads();

    const int wid = tid >> 6, lane = tid & 63, quad = lane >> 4, m16 = lane & 15;
    const int pg = wid % G, oc = wid / G;
    const int o_off = oc * OT * 16;
    const int pixr = pg * 16 + m16;
    const int gl4 = (tid % GL) * 4;
    const int grp = tid / GL;

    f32x4 acc[OT];
    #pragma unroll
    for (int t = 0; t < OT; ++t) acc[t] = (f32x4){0.f, 0.f, 0.f, 0.f};

    for (int ng = 0; ng < 9; ng += NU) {
        if (ng) __syncthreads();   // xoff reuse safe
        // ---- phase 2: cooperative gather into LDS xoff ----
        #pragma unroll 2
        for (int task = grp; task < MTILE * NU; task += NGRP) {
            int pix = task % MTILE;
            int nn = task / MTILE;
            int n = ng + nn;
            const float* ibp = x + imgb[pix] + gl4;
            f4 r;
            if constexpr (DEF) {
                i4v ti = tbl_i[pix][n];
                f4  tw = tbl_w[pix][n];
                f4 a = *(const f4*)(ibp + ti[0]);
                f4 b = *(const f4*)(ibp + ti[1]);
                f4 c = *(const f4*)(ibp + ti[2]);
                f4 d = *(const f4*)(ibp + ti[3]);
                r = a * tw[0] + b * tw[1] + c * tw[2] + d * tw[3];
            } else {
                r = *(const f4*)(ibp + tbl_o[pix][n]) * tbl_s[pix][n];
            }
            ushort4 pk;
            pk.x = f2bf(r[0]); pk.y = f2bf(r[1]);
            pk.z = f2bf(r[2]); pk.w = f2bf(r[3]);
            *(ushort4*)&xoff[pix * KPL + nn * C + gl4] = pk;
        }
        // ---- phase 3: chunked weight staging + MFMA ----
        for (int ch = 0; ch < NU * C / 32; ++ch) {
            __syncthreads();                 // gather done / wt reuse safe
            const int k0g = ng * C + ch * 32;
            #pragma unroll
            for (int pass = 0; pass < OPAD / 32; ++pass) {
                int o = pass * 32 + (tid >> 3);
                int kk = (tid & 7) * 4;
                *(ushort4*)&wt[o * 40 + kk] =
                    *(const ushort4*)(wq + (size_t)o * K + k0g + kk);
            }
            __syncthreads();
            const int kl = ch * 32 + quad * 8;
            short8 bfrag = *(const short8*)&xoff[pixr * KPL + kl];
            #pragma unroll
            for (int t = 0; t < OT; ++t) {
                short8 af = *(const short8*)&wt[(o_off + t * 16 + m16) * 40 + quad * 8];
                acc[t] = __builtin_amdgcn_mfma_f32_16x16x32_bf16(af, bfrag, acc[t], 0, 0, 0);
            }
        }
    }

    // ---- epilogue ----
    const int p = p0 + pixr;
    if constexpr (BN) {
        #pragma unroll
        for (int t = 0; t < OT; ++t) {
            int o = o_off + t * 16 + quad * 4;
            f4 r;
            #pragma unroll
            for (int rr = 0; rr < 4; ++rr)
                r[rr] = fmaxf(fmaf(acc[t][rr], scb[o + rr], shb[o + rr]), 0.f);
            *(f4*)(out + (size_t)p * OPAD + o) = r;
        }
    } else {
        int b = p / OHW, rem = p % OHW;
        int i = rem / OW, j = rem % OW;
        #pragma unroll
        for (int t = 0; t < OT; ++t) {
            #pragma unroll
            for (int rr = 0; rr < 4; ++rr) {
                int o = o_off + t * 16 + quad * 4 + rr;
                if (o < OREAL)
                    out[((size_t)(b * 18 + o) * OH + i) * OW + j] = acc[t][rr] + q0[o];
            }
        }
    }
}

// ---------------- global avg pool (8x8, NHWC) + FC 128->100 ----------------
__global__ __launch_bounds__(128)
void pool_fc(const float* __restrict__ h4, const float* __restrict__ wcls,
             const float* __restrict__ bcls, float* __restrict__ out)
{
    __shared__ float pool[128];
    int b = blockIdx.x;
    int tid = threadIdx.x;
    const float* src = h4 + (size_t)b * 8192;
    float s = 0.f;
    #pragma unroll
    for (int t = 0; t < 64; ++t) s += src[t * 128 + tid];
    pool[tid] = s * (1.f / 64.f);
    __syncthreads();
    if (tid < 100) {
        float acc = bcls[tid];
        const float* wr = wcls + tid * 128;
        #pragma unroll
        for (int c = 0; c < 128; ++c) acc = fmaf(pool[c], wr[c], acc);
        out[(size_t)b * 100 + tid] = acc;
    }
}

extern "C" void kernel_launch(void* const* d_in, const int* in_sizes, int n_in,
                              void* d_out, int out_size, void* d_ws, size_t ws_size,
                              hipStream_t stream)
{
    const float* x    = (const float*)d_in[0];
    const float* w1   = (const float*)d_in[1];
    const float* b1   = (const float*)d_in[2];
    const float* g1   = (const float*)d_in[3];
    const float* be1  = (const float*)d_in[4];
    const float* m1   = (const float*)d_in[5];
    const float* v1   = (const float*)d_in[6];
    const float* wp2  = (const float*)d_in[7];
    const float* bp2  = (const float*)d_in[8];
    const float* wc2  = (const float*)d_in[9];
    const float* g2   = (const float*)d_in[10];
    const float* be2  = (const float*)d_in[11];
    const float* m2   = (const float*)d_in[12];
    const float* v2   = (const float*)d_in[13];
    const float* wp3  = (const float*)d_in[14];
    const float* bp3  = (const float*)d_in[15];
    const float* wc3  = (const float*)d_in[16];
    const float* g3   = (const float*)d_in[17];
    const float* be3  = (const float*)d_in[18];
    const float* m3   = (const float*)d_in[19];
    const float* v3   = (const float*)d_in[20];
    const float* wp4  = (const float*)d_in[21];
    const float* bp4  = (const float*)d_in[22];
    const float* wc4  = (const float*)d_in[23];
    const float* g4   = (const float*)d_in[24];
    const float* be4  = (const float*)d_in[25];
    const float* m4   = (const float*)d_in[26];
    const float* v4   = (const float*)d_in[27];
    const float* wcls = (const float*)d_in[28];
    const float* bcls = (const float*)d_in[29];
    float* out = (float*)d_out;

    float* ws  = (float*)d_ws;
    float* h1  = ws;                  // NHWC 256*32*32*32 = 8,388,608 f32
    float* off = h1 + 8388608;        // NCHW max 256*18*16*16 = 1,179,648 (reused)
    float* h2  = off + 1179648;       // NHWC 256*16*16*64 = 4,194,304
    float* h3  = h2 + 4194304;        // NHWC 256*16*16*128 = 8,388,608
    float* h4  = h3 + 8388608;        // NHWC 256*8*8*128 = 2,097,152
    unsigned short* wc2b = (unsigned short*)(h4 + 2097152);  // 64*288
    unsigned short* wc3b = wc2b + 18432;       // 128*576
    unsigned short* wc4b = wc3b + 73728;       // 128*1152
    unsigned short* wp2b = wc4b + 147456;      // 32*288
    unsigned short* wp3b = wp2b + 9216;        // 32*576
    unsigned short* wp4b = wp3b + 18432;       // 32*1152
    unsigned short* wq1  = wp4b + 36864;       // 32*32
    (void)ws_size; (void)in_sizes; (void)n_in; (void)out_size;

    CvtArgs ca;
    ca.s[0] = { wc2, wc2b, 64, 32, 288, 18432 };
    ca.s[1] = { wc3, wc3b, 128, 64, 576, 92160 };
    ca.s[2] = { wc4, wc4b, 128, 128, 1152, 239616 };
    ca.s[3] = { wp2, wp2b, 18, 32, 288, 248832 };
    ca.s[4] = { wp3, wp3b, 18, 64, 576, 267264 };
    ca.s[5] = { wp4, wp4b, 18, 128, 1152, 304128 };
    ca.s[6] = { w1, wq1, 32, 3, 32, 305152 };
    cvt_all<<<1192, 256, 0, stream>>>(ca);

    // Layer 1: conv 3->32 (image-in-LDS MFMA), NCHW in, NHWC out
    conv1_tile<<<256, 256, 0, stream>>>(x, wq1, b1, g1, be1, m1, v1, h1);

    // Layer 2: 32x32 -> 16x16, stride 2, C=32 -> O=64
    conv_tile<32, 18, 32, 32, 32, 16, 16, 2, 32, 9, false, false><<<2048, 256, 0, stream>>>(
        h1, nullptr, wp2b, bp2, nullptr, nullptr, nullptr, off);
    conv_tile<32, 64, 64, 32, 32, 16, 16, 2, 32, 9, true, true><<<2048, 256, 0, stream>>>(
        h1, off, wc2b, g2, be2, m2, v2, h2);

    // Layer 3: 16x16 -> 16x16, stride 1, C=64 -> O=128
    conv_tile<64, 18, 32, 16, 16, 16, 16, 1, 32, 9, false, false><<<2048, 256, 0, stream>>>(
        h2, nullptr, wp3b, bp3, nullptr, nullptr, nullptr, off);
    conv_tile<64, 128, 128, 16, 16, 16, 16, 1, 32, 9, true, true><<<2048, 256, 0, stream>>>(
        h2, off, wc3b, g3, be3, m3, v3, h3);

    // Layer 4: 16x16 -> 8x8, stride 2, C=128 -> O=128
    conv_tile<128, 18, 32, 16, 16, 8, 8, 2, 32, 3, false, false><<<512, 256, 0, stream>>>(
        h3, nullptr, wp4b, bp4, nullptr, nullptr, nullptr, off);
    conv_tile<128, 128, 128, 16, 16, 8, 8, 2, 16, 9, true, true><<<1024, 256, 0, stream>>>(
        h3, off, wc4b, g4, be4, m4, v4, h4);

    // Pool + FC
    pool_fc<<<256, 128, 0, stream>>>(h4, wcls, bcls, out);
}

// Round 5
// 266.572 us; speedup vs baseline: 6.3915x; 1.1982x over previous
//
#include <hip/hip_runtime.h>
#include <math.h>

#define BN_EPS 1e-5f

typedef __attribute__((ext_vector_type(4))) float f4;
typedef __attribute__((ext_vector_type(4))) int i4v;
typedef __attribute__((ext_vector_type(8))) short short8;
typedef __attribute__((ext_vector_type(4))) float f32x4;

__device__ inline unsigned short f2bf(float f) {
    unsigned int u = __builtin_bit_cast(unsigned int, f);
    return (unsigned short)((u + 0x7FFFu + ((u >> 16) & 1u)) >> 16);
}
__device__ inline float blo(int u) { return __builtin_bit_cast(float, (int)(u << 16)); }
__device__ inline float bhi(int u) { return __builtin_bit_cast(float, (int)(u & 0xffff0000)); }
__device__ inline int pkbf(float a, float b) {   // a -> low short, b -> high short, RNE
    unsigned ua = __builtin_bit_cast(unsigned, a);
    unsigned ub = __builtin_bit_cast(unsigned, b);
    ua = (ua + 0x7FFFu + ((ua >> 16) & 1u)) >> 16;
    ub = (ub + 0x7FFFu + ((ub >> 16) & 1u)) & 0xFFFF0000u;
    return (int)(ua | ub);
}

// ---------------- fused weight conversion: all 7 weight tensors ----------------
// dst[o][k] bf16 with k = n*C + c permutation; zero-pads o>=oreal, k>=9C.
struct CvtSeg { const float* src; unsigned short* dst; int oreal, c, kpad, end; };
struct CvtArgs { CvtSeg s[7]; };

__global__ __launch_bounds__(256)
void cvt_all(CvtArgs a)
{
    int idx = blockIdx.x * 256 + threadIdx.x;
    int base = 0;
    #pragma unroll
    for (int i = 0; i < 7; ++i) {
        if (idx < a.s[i].end) {
            int local = idx - base;
            int kpad = a.s[i].kpad, c = a.s[i].c;
            int o = local / kpad, k = local - o * kpad;
            unsigned short val = 0;
            if (o < a.s[i].oreal && k < 9 * c) {
                int n = k / c, cc = k - n * c;
                val = f2bf(a.s[i].src[(o * c + cc) * 9 + n]);
            }
            a.s[i].dst[local] = val;
            return;
        }
        base = a.s[i].end;
    }
}

// ---------------- layer 1: image in LDS + MFMA, NCHW f32 in -> NHWC bf16 out ----------------
__global__ __launch_bounds__(256)
void conv1_tile(const float* __restrict__ x, const unsigned short* __restrict__ wq,
                const float* __restrict__ bias, const float* __restrict__ g,
                const float* __restrict__ be, const float* __restrict__ m,
                const float* __restrict__ v, unsigned short* __restrict__ out)
{
    __shared__ __align__(16) float img[3072];
    __shared__ __align__(16) unsigned short wt[32 * 40];
    __shared__ float scb[32], shb[32];
    const int tid = threadIdx.x;
    const int b = blockIdx.x >> 2;
    const int qtr = blockIdx.x & 3;
    if (tid < 32) {
        float sc = g[tid] * rsqrtf(v[tid] + BN_EPS);
        scb[tid] = sc;
        shb[tid] = be[tid] - m[tid] * sc + bias[tid] * sc;
    }
    *(ushort4*)&wt[(tid >> 3) * 40 + (tid & 7) * 4] =
        *(const ushort4*)(wq + (tid >> 3) * 32 + (tid & 7) * 4);
    const float* xb = x + (size_t)b * 3072;
    #pragma unroll
    for (int r = 0; r < 3; ++r) {
        int idx = r * 256 + tid;
        *(f4*)&img[idx * 4] = *(const f4*)(xb + idx * 4);
    }
    __syncthreads();
    const int wid = tid >> 6, lane = tid & 63, quad = lane >> 4, m16 = lane & 15;
    short8 af0 = *(const short8*)&wt[m16 * 40 + quad * 8];
    short8 af1 = *(const short8*)&wt[(16 + m16) * 40 + quad * 8];
    #pragma unroll
    for (int it = 0; it < 4; ++it) {
        int pix = qtr * 256 + it * 64 + wid * 16 + m16;
        int i = pix >> 5, j = pix & 31;
        short8 bfrag;
        #pragma unroll
        for (int jj = 0; jj < 8; ++jj) {
            int k = quad * 8 + jj;
            float val = 0.f;
            if (k < 27) {
                int n = k / 3, c = k - n * 3;
                int u = i - 1 + n / 3, vv = j - 1 + n % 3;
                if (u >= 0 && u < 32 && vv >= 0 && vv < 32)
                    val = img[c * 1024 + u * 32 + vv];
            }
            bfrag[jj] = (short)f2bf(val);
        }
        f32x4 a0 = {0.f,0.f,0.f,0.f}, a1 = {0.f,0.f,0.f,0.f};
        a0 = __builtin_amdgcn_mfma_f32_16x16x32_bf16(af0, bfrag, a0, 0, 0, 0);
        a1 = __builtin_amdgcn_mfma_f32_16x16x32_bf16(af1, bfrag, a1, 0, 0, 0);
        unsigned short* op = out + ((size_t)b * 1024 + pix) * 32;
        ushort4 s0, s1;
        #pragma unroll
        for (int rr = 0; rr < 4; ++rr) {
            int o0 = quad * 4 + rr, o1 = 16 + quad * 4 + rr;
            ((unsigned short*)&s0)[rr] = f2bf(fmaxf(fmaf(a0[rr], scb[o0], shb[o0]), 0.f));
            ((unsigned short*)&s1)[rr] = f2bf(fmaxf(fmaf(a1[rr], scb[o1], shb[o1]), 0.f));
        }
        *(ushort4*)(op + quad * 4) = s0;
        *(ushort4*)(op + 16 + quad * 4) = s1;
    }
}

// ---------------- unified deform/offset conv: reg-weights + dbuf LDS xoff ----------------
// out[p][o] = sum_k B[p][k]*wq[o][k], k = n*C+c. Activations bf16 NHWC.
// Per n: gather n+1 (cooperative, inline bilinear table) -> LDS buf^1,
// prefetch weight frags n+1 (registers, from L2), MFMA over buf (1 sync/n).
template<int C, int OREAL, int OPAD, int H, int W, int OH, int OW, int S,
         int MTILE, bool DEF, bool BN>
__global__ __launch_bounds__(256, 3)
void dconv(const unsigned short* __restrict__ xact, const float* __restrict__ offp,
           const unsigned short* __restrict__ wq,
           const float* __restrict__ q0, const float* __restrict__ q1,
           const float* __restrict__ q2, const float* __restrict__ q3,
           void* __restrict__ outv)
{
    constexpr int K = C * 9;
    constexpr int KCH = C / 32;                 // k-chunks per n
    constexpr int OSPLIT = (OPAD >= 64) ? 4 : 2;
    constexpr int G = 4 / OSPLIT;
    constexpr int OT = OPAD / (16 * OSPLIT);
    constexpr int PW = MTILE / G;
    constexpr int ST = PW / 16;
    constexpr int CP = C + 8;                   // xoff row stride (shorts)
    constexpr int GL = C / 8;                   // lanes per gather task
    constexpr int NGRP = 256 / GL;
    constexpr int NT_ITER = MTILE / NGRP;
    constexpr int OHW = OH * OW;
    constexpr int HWC = H * W * C;
    constexpr int Hp = H + 2, Wp = W + 2;
    static_assert(MTILE % NGRP == 0 && PW % 16 == 0, "tiling");

    __shared__ __align__(16) unsigned short xo[2][MTILE * CP];
    __shared__ float scb[OPAD], shb[OPAD];

    const int tid = threadIdx.x;
    const int p0 = blockIdx.x * MTILE;

    if (BN) {
        for (int o = tid; o < OREAL; o += 256) {
            float sc = q0[o] * rsqrtf(q3[o] + BN_EPS);
            scb[o] = sc;
            shb[o] = q1[o] - q2[o] * sc;
        }
    } else {
        for (int o = tid; o < OREAL; o += 256) scb[o] = q0[o];
    }

    const int gl = tid % GL;
    const int grp = tid / GL;
    const int wid = tid >> 6, lane = tid & 63, quad = lane >> 4, m16 = lane & 15;
    const int og = wid % OSPLIT, pg = wid / OSPLIT;
    const int obase = og * OT * 16;
    const int pixbase = pg * PW;

    auto do_gather = [&](int n, int buf) {
        #pragma unroll
        for (int it = 0; it < NT_ITER; ++it) {
            const int pix = it * NGRP + grp;
            const int p = p0 + pix;
            const int b = p / OHW;
            const int rem = p % OHW;
            const int i = rem / OW, j = rem % OW;
            const unsigned short* xb = xact + (size_t)b * HWC + gl * 8;
            i4v R;
            if constexpr (DEF) {
                float ox = offp[((size_t)(b * 18 + n) * OH + i) * OW + j];
                float oy = offp[((size_t)(b * 18 + 9 + n) * OH + i) * OW + j];
                float px = (float)(i * S + n / 3) + ox;
                float py = (float)(j * S + n % 3) + oy;
                int qx0 = (int)floorf(px), qy0 = (int)floorf(py);
                int x0 = min(max(qx0, 0), Hp - 1), x1 = min(max(qx0 + 1, 0), Hp - 1);
                int y0 = min(max(qy0, 0), Wp - 1), y1 = min(max(qy0 + 1, 0), Wp - 1);
                float pxc = fminf(fmaxf(px, 0.f), (float)(Hp - 1));
                float pyc = fminf(fmaxf(py, 0.f), (float)(Wp - 1));
                float gx0 = 1.f + ((float)x0 - pxc), gx1 = 1.f - ((float)x1 - pxc);
                float gy0 = 1.f + ((float)y0 - pyc), gy1 = 1.f - ((float)y1 - pyc);
                int u0 = x0 - 1, u1 = x1 - 1, v0 = y0 - 1, v1 = y1 - 1;
                bool k0 = (u0 >= 0 && u0 < H && v0 >= 0 && v0 < W);
                bool k1 = (u1 >= 0 && u1 < H && v1 >= 0 && v1 < W);
                bool k2 = (u0 >= 0 && u0 < H && v1 >= 0 && v1 < W);
                bool k3 = (u1 >= 0 && u1 < H && v0 >= 0 && v0 < W);
                int t0 = k0 ? (u0 * W + v0) * C : 0;  float w0 = k0 ? gx0 * gy0 : 0.f;
                int t1 = k1 ? (u1 * W + v1) * C : 0;  float w1 = k1 ? gx1 * gy1 : 0.f;
                int t2 = k2 ? (u0 * W + v1) * C : 0;  float w2 = k2 ? gx0 * gy1 : 0.f;
                int t3 = k3 ? (u1 * W + v0) * C : 0;  float w3 = k3 ? gx1 * gy0 : 0.f;
                i4v A = *(const i4v*)(xb + t0);
                i4v Bv = *(const i4v*)(xb + t1);
                i4v Cv = *(const i4v*)(xb + t2);
                i4v Dv = *(const i4v*)(xb + t3);
                #pragma unroll
                for (int e = 0; e < 4; ++e) {
                    float lo = w0 * blo(A[e]);
                    lo = fmaf(w1, blo(Bv[e]), lo);
                    lo = fmaf(w2, blo(Cv[e]), lo);
                    lo = fmaf(w3, blo(Dv[e]), lo);
                    float hi = w0 * bhi(A[e]);
                    hi = fmaf(w1, bhi(Bv[e]), hi);
                    hi = fmaf(w2, bhi(Cv[e]), hi);
                    hi = fmaf(w3, bhi(Dv[e]), hi);
                    R[e] = pkbf(lo, hi);
                }
            } else {
                int u = i * S - 1 + n / 3, vv = j * S - 1 + n % 3;
                bool ok = (u >= 0 && u < H && vv >= 0 && vv < W);
                if (ok) R = *(const i4v*)(xb + (u * W + vv) * C);
                else    R = (i4v){0, 0, 0, 0};
            }
            *(i4v*)&xo[buf][pix * CP + gl * 8] = R;
        }
    };

    auto load_wf = [&](int n, short8 (*wf)[OT]) {
        #pragma unroll
        for (int ch = 0; ch < KCH; ++ch)
            #pragma unroll
            for (int t = 0; t < OT; ++t)
                wf[ch][t] = *(const short8*)(wq + (size_t)(obase + t * 16 + m16) * K
                                             + n * C + ch * 32 + quad * 8);
    };

    f32x4 acc[ST][OT];
    #pragma unroll
    for (int st = 0; st < ST; ++st)
        #pragma unroll
        for (int t = 0; t < OT; ++t) acc[st][t] = (f32x4){0.f, 0.f, 0.f, 0.f};

    short8 wfA[KCH][OT], wfB[KCH][OT];
    do_gather(0, 0);
    load_wf(0, wfA);
    __syncthreads();

    for (int n = 0; n < 9; ++n) {
        const int cur = n & 1;
        if (n < 8) {
            do_gather(n + 1, cur ^ 1);
            load_wf(n + 1, wfB);
        }
        #pragma unroll
        for (int ch = 0; ch < KCH; ++ch)
            #pragma unroll
            for (int st = 0; st < ST; ++st) {
                short8 bf = *(const short8*)&xo[cur][(pixbase + st * 16 + m16) * CP
                                                    + ch * 32 + quad * 8];
                #pragma unroll
                for (int t = 0; t < OT; ++t)
                    acc[st][t] = __builtin_amdgcn_mfma_f32_16x16x32_bf16(
                        wfA[ch][t], bf, acc[st][t], 0, 0, 0);
            }
        if (n < 8) {
            #pragma unroll
            for (int ch = 0; ch < KCH; ++ch)
                #pragma unroll
                for (int t = 0; t < OT; ++t) wfA[ch][t] = wfB[ch][t];
        }
        __syncthreads();
    }

    if constexpr (BN) {
        unsigned short* outw = (unsigned short*)outv;
        #pragma unroll
        for (int st = 0; st < ST; ++st) {
            const int p = p0 + pixbase + st * 16 + m16;
            #pragma unroll
            for (int t = 0; t < OT; ++t) {
                int o = obase + t * 16 + quad * 4;
                ushort4 s;
                #pragma unroll
                for (int rr = 0; rr < 4; ++rr)
                    ((unsigned short*)&s)[rr] =
                        f2bf(fmaxf(fmaf(acc[st][t][rr], scb[o + rr], shb[o + rr]), 0.f));
                *(ushort4*)(outw + (size_t)p * OPAD + o) = s;
            }
        }
    } else {
        float* outf = (float*)outv;
        #pragma unroll
        for (int st = 0; st < ST; ++st) {
            const int p = p0 + pixbase + st * 16 + m16;
            const int b = p / OHW, rem = p % OHW;
            const int i = rem / OW, j = rem % OW;
            #pragma unroll
            for (int t = 0; t < OT; ++t)
                #pragma unroll
                for (int rr = 0; rr < 4; ++rr) {
                    int o = obase + t * 16 + quad * 4 + rr;
                    if (o < OREAL)
                        outf[((size_t)(b * 18 + o) * OH + i) * OW + j] =
                            acc[st][t][rr] + scb[o];
                }
        }
    }
}

// ---------------- global avg pool (8x8, NHWC bf16) + FC 128->100 ----------------
__global__ __launch_bounds__(128)
void pool_fc(const unsigned short* __restrict__ h4, const float* __restrict__ wcls,
             const float* __restrict__ bcls, float* __restrict__ out)
{
    __shared__ float pool[128];
    int b = blockIdx.x;
    int tid = threadIdx.x;
    const unsigned short* src = h4 + (size_t)b * 8192;
    float s = 0.f;
    #pragma unroll
    for (int t = 0; t < 64; ++t)
        s += __builtin_bit_cast(float, (unsigned)src[t * 128 + tid] << 16);
    pool[tid] = s * (1.f / 64.f);
    __syncthreads();
    if (tid < 100) {
        float acc = bcls[tid];
        const float* wr = wcls + tid * 128;
        #pragma unroll
        for (int c = 0; c < 128; ++c) acc = fmaf(pool[c], wr[c], acc);
        out[(size_t)b * 100 + tid] = acc;
    }
}

extern "C" void kernel_launch(void* const* d_in, const int* in_sizes, int n_in,
                              void* d_out, int out_size, void* d_ws, size_t ws_size,
                              hipStream_t stream)
{
    const float* x    = (const float*)d_in[0];
    const float* w1   = (const float*)d_in[1];
    const float* b1   = (const float*)d_in[2];
    const float* g1   = (const float*)d_in[3];
    const float* be1  = (const float*)d_in[4];
    const float* m1   = (const float*)d_in[5];
    const float* v1   = (const float*)d_in[6];
    const float* wp2  = (const float*)d_in[7];
    const float* bp2  = (const float*)d_in[8];
    const float* wc2  = (const float*)d_in[9];
    const float* g2   = (const float*)d_in[10];
    const float* be2  = (const float*)d_in[11];
    const float* m2   = (const float*)d_in[12];
    const float* v2   = (const float*)d_in[13];
    const float* wp3  = (const float*)d_in[14];
    const float* bp3  = (const float*)d_in[15];
    const float* wc3  = (const float*)d_in[16];
    const float* g3   = (const float*)d_in[17];
    const float* be3  = (const float*)d_in[18];
    const float* m3   = (const float*)d_in[19];
    const float* v3   = (const float*)d_in[20];
    const float* wp4  = (const float*)d_in[21];
    const float* bp4  = (const float*)d_in[22];
    const float* wc4  = (const float*)d_in[23];
    const float* g4   = (const float*)d_in[24];
    const float* be4  = (const float*)d_in[25];
    const float* m4   = (const float*)d_in[26];
    const float* v4   = (const float*)d_in[27];
    const float* wcls = (const float*)d_in[28];
    const float* bcls = (const float*)d_in[29];
    float* out = (float*)d_out;

    float* ws  = (float*)d_ws;
    float* off = ws;                               // fp32 NCHW, max 1,179,648 (reused)
    unsigned short* h1 = (unsigned short*)(off + 1179648);  // NHWC bf16 256*1024*32
    unsigned short* h2 = h1 + 8388608;             // 256*256*64
    unsigned short* h3 = h2 + 4194304;             // 256*256*128
    unsigned short* h4 = h3 + 8388608;             // 256*64*128
    unsigned short* wc2b = h4 + 2097152;           // 64*288
    unsigned short* wc3b = wc2b + 18432;           // 128*576
    unsigned short* wc4b = wc3b + 73728;           // 128*1152
    unsigned short* wp2b = wc4b + 147456;          // 32*288
    unsigned short* wp3b = wp2b + 9216;            // 32*576
    unsigned short* wp4b = wp3b + 18432;           // 32*1152
    unsigned short* wq1  = wp4b + 36864;           // 32*32
    (void)ws_size; (void)in_sizes; (void)n_in; (void)out_size;

    CvtArgs ca;
    ca.s[0] = { wc2, wc2b, 64, 32, 288, 18432 };
    ca.s[1] = { wc3, wc3b, 128, 64, 576, 92160 };
    ca.s[2] = { wc4, wc4b, 128, 128, 1152, 239616 };
    ca.s[3] = { wp2, wp2b, 18, 32, 288, 248832 };
    ca.s[4] = { wp3, wp3b, 18, 64, 576, 267264 };
    ca.s[5] = { wp4, wp4b, 18, 128, 1152, 304128 };
    ca.s[6] = { w1, wq1, 32, 3, 32, 305152 };
    cvt_all<<<1192, 256, 0, stream>>>(ca);

    // Layer 1
    conv1_tile<<<1024, 256, 0, stream>>>(x, wq1, b1, g1, be1, m1, v1, h1);

    // Layer 2: 32x32 -> 16x16, stride 2, C=32 -> O=64
    dconv<32, 18, 32, 32, 32, 16, 16, 2, 128, false, false><<<512, 256, 0, stream>>>(
        h1, nullptr, wp2b, bp2, nullptr, nullptr, nullptr, off);
    dconv<32, 64, 64, 32, 32, 16, 16, 2, 128, true, true><<<512, 256, 0, stream>>>(
        h1, off, wc2b, g2, be2, m2, v2, h2);

    // Layer 3: 16x16 -> 16x16, stride 1, C=64 -> O=128
    dconv<64, 18, 32, 16, 16, 16, 16, 1, 128, false, false><<<512, 256, 0, stream>>>(
        h2, nullptr, wp3b, bp3, nullptr, nullptr, nullptr, off);
    dconv<64, 128, 128, 16, 16, 16, 16, 1, 128, true, true><<<512, 256, 0, stream>>>(
        h2, off, wc3b, g3, be3, m3, v3, h3);

    // Layer 4: 16x16 -> 8x8, stride 2, C=128 -> O=128
    dconv<128, 18, 32, 16, 16, 8, 8, 2, 32, false, false><<<512, 256, 0, stream>>>(
        h3, nullptr, wp4b, bp4, nullptr, nullptr, nullptr, off);
    dconv<128, 128, 128, 16, 16, 8, 8, 2, 32, true, true><<<512, 256, 0, stream>>>(
        h3, off, wc4b, g4, be4, m4, v4, h4);

    // Pool + FC
    pool_fc<<<256, 128, 0, stream>>>(h4, wcls, bcls, out);
}

// Round 6
// 251.591 us; speedup vs baseline: 6.7721x; 1.0595x over previous
//
#include <hip/hip_runtime.h>
#include <math.h>

#define BN_EPS 1e-5f

typedef __attribute__((ext_vector_type(4))) float f4;
typedef __attribute__((ext_vector_type(4))) int i4v;
typedef __attribute__((ext_vector_type(8))) short short8;
typedef __attribute__((ext_vector_type(4))) float f32x4;

__device__ inline unsigned short f2bf(float f) {
    unsigned int u = __builtin_bit_cast(unsigned int, f);
    return (unsigned short)((u + 0x7FFFu + ((u >> 16) & 1u)) >> 16);
}
__device__ inline float blo(int u) { return __builtin_bit_cast(float, (int)(u << 16)); }
__device__ inline float bhi(int u) { return __builtin_bit_cast(float, (int)(u & 0xffff0000)); }
__device__ inline int pkbf(float a, float b) {   // a -> low short, b -> high short, RNE
    unsigned ua = __builtin_bit_cast(unsigned, a);
    unsigned ub = __builtin_bit_cast(unsigned, b);
    ua = (ua + 0x7FFFu + ((ua >> 16) & 1u)) >> 16;
    ub = (ub + 0x7FFFu + ((ub >> 16) & 1u)) & 0xFFFF0000u;
    return (int)(ua | ub);
}

// ---------------- fused weight conversion: all 7 weight tensors ----------------
struct CvtSeg { const float* src; unsigned short* dst; int oreal, c, kpad, end; };
struct CvtArgs { CvtSeg s[7]; };

__global__ __launch_bounds__(256)
void cvt_all(CvtArgs a)
{
    int idx = blockIdx.x * 256 + threadIdx.x;
    int base = 0;
    #pragma unroll
    for (int i = 0; i < 7; ++i) {
        if (idx < a.s[i].end) {
            int local = idx - base;
            int kpad = a.s[i].kpad, c = a.s[i].c;
            int o = local / kpad, k = local - o * kpad;
            unsigned short val = 0;
            if (o < a.s[i].oreal && k < 9 * c) {
                int n = k / c, cc = k - n * c;
                val = f2bf(a.s[i].src[(o * c + cc) * 9 + n]);
            }
            a.s[i].dst[local] = val;
            return;
        }
        base = a.s[i].end;
    }
}

// ---------------- layer 1: image in LDS + MFMA, NCHW f32 in -> NHWC bf16 out ----------------
__global__ __launch_bounds__(256)
void conv1_tile(const float* __restrict__ x, const unsigned short* __restrict__ wq,
                const float* __restrict__ bias, const float* __restrict__ g,
                const float* __restrict__ be, const float* __restrict__ m,
                const float* __restrict__ v, unsigned short* __restrict__ out)
{
    __shared__ __align__(16) float img[3072];
    __shared__ __align__(16) unsigned short wt[32 * 40];
    __shared__ float scb[32], shb[32];
    const int tid = threadIdx.x;
    const int b = blockIdx.x >> 2;
    const int qtr = blockIdx.x & 3;
    if (tid < 32) {
        float sc = g[tid] * rsqrtf(v[tid] + BN_EPS);
        scb[tid] = sc;
        shb[tid] = be[tid] - m[tid] * sc + bias[tid] * sc;
    }
    *(ushort4*)&wt[(tid >> 3) * 40 + (tid & 7) * 4] =
        *(const ushort4*)(wq + (tid >> 3) * 32 + (tid & 7) * 4);
    const float* xb = x + (size_t)b * 3072;
    #pragma unroll
    for (int r = 0; r < 3; ++r) {
        int idx = r * 256 + tid;
        *(f4*)&img[idx * 4] = *(const f4*)(xb + idx * 4);
    }
    __syncthreads();
    const int wid = tid >> 6, lane = tid & 63, quad = lane >> 4, m16 = lane & 15;
    short8 af0 = *(const short8*)&wt[m16 * 40 + quad * 8];
    short8 af1 = *(const short8*)&wt[(16 + m16) * 40 + quad * 8];
    #pragma unroll
    for (int it = 0; it < 4; ++it) {
        int pix = qtr * 256 + it * 64 + wid * 16 + m16;
        int i = pix >> 5, j = pix & 31;
        short8 bfrag;
        #pragma unroll
        for (int jj = 0; jj < 8; ++jj) {
            int k = quad * 8 + jj;
            float val = 0.f;
            if (k < 27) {
                int n = k / 3, c = k - n * 3;
                int u = i - 1 + n / 3, vv = j - 1 + n % 3;
                if (u >= 0 && u < 32 && vv >= 0 && vv < 32)
                    val = img[c * 1024 + u * 32 + vv];
            }
            bfrag[jj] = (short)f2bf(val);
        }
        f32x4 a0 = {0.f,0.f,0.f,0.f}, a1 = {0.f,0.f,0.f,0.f};
        a0 = __builtin_amdgcn_mfma_f32_16x16x32_bf16(af0, bfrag, a0, 0, 0, 0);
        a1 = __builtin_amdgcn_mfma_f32_16x16x32_bf16(af1, bfrag, a1, 0, 0, 0);
        unsigned short* op = out + ((size_t)b * 1024 + pix) * 32;
        ushort4 s0, s1;
        #pragma unroll
        for (int rr = 0; rr < 4; ++rr) {
            int o0 = quad * 4 + rr, o1 = 16 + quad * 4 + rr;
            ((unsigned short*)&s0)[rr] = f2bf(fmaxf(fmaf(a0[rr], scb[o0], shb[o0]), 0.f));
            ((unsigned short*)&s1)[rr] = f2bf(fmaxf(fmaf(a1[rr], scb[o1], shb[o1]), 0.f));
        }
        *(ushort4*)(op + quad * 4) = s0;
        *(ushort4*)(op + 16 + quad * 4) = s1;
    }
}

// ---------------- unified deform/offset conv: reg-weights + dbuf LDS xoff ----------------
template<int C, int OREAL, int OPAD, int H, int W, int OH, int OW, int S,
         int MTILE, bool DEF, bool BN>
__global__ __launch_bounds__(256, 4)
void dconv(const unsigned short* __restrict__ xact, const float* __restrict__ offp,
           const unsigned short* __restrict__ wq,
           const float* __restrict__ q0, const float* __restrict__ q1,
           const float* __restrict__ q2, const float* __restrict__ q3,
           void* __restrict__ outv)
{
    constexpr int K = C * 9;
    constexpr int KCH = C / 32;                 // k-chunks per n
    constexpr int OSPLIT = (OPAD >= 64) ? 4 : 2;
    constexpr int G = 4 / OSPLIT;
    constexpr int OT = OPAD / (16 * OSPLIT);
    constexpr int PW = MTILE / G;
    constexpr int ST = PW / 16;
    constexpr int CP = C + 8;                   // xoff row stride (shorts)
    constexpr int GL = C / 8;                   // lanes per gather task
    constexpr int NGRP = 256 / GL;
    constexpr int NT_ITER = MTILE / NGRP;
    constexpr int OHW = OH * OW;
    constexpr int HWC = H * W * C;
    constexpr int Hp = H + 2, Wp = W + 2;
    static_assert(MTILE % NGRP == 0 && PW % 16 == 0, "tiling");

    __shared__ __align__(16) unsigned short xo[2][MTILE * CP];
    __shared__ float scb[OPAD], shb[OPAD];

    const int tid = threadIdx.x;
    const int p0 = blockIdx.x * MTILE;

    if (BN) {
        for (int o = tid; o < OREAL; o += 256) {
            float sc = q0[o] * rsqrtf(q3[o] + BN_EPS);
            scb[o] = sc;
            shb[o] = q1[o] - q2[o] * sc;
        }
    } else {
        for (int o = tid; o < OREAL; o += 256) scb[o] = q0[o];
    }

    const int gl = tid % GL;
    const int grp = tid / GL;
    const int wid = tid >> 6, lane = tid & 63, quad = lane >> 4, m16 = lane & 15;
    const int og = wid % OSPLIT, pg = wid / OSPLIT;
    const int obase = og * OT * 16;
    const int pixbase = pg * PW;

    auto do_gather = [&](int n, int buf) {
        #pragma unroll
        for (int it = 0; it < NT_ITER; ++it) {
            const int pix = it * NGRP + grp;
            const int p = p0 + pix;
            const int b = p / OHW;
            const int rem = p % OHW;
            const int i = rem / OW, j = rem % OW;
            const unsigned short* xb = xact + (size_t)b * HWC + gl * 8;
            i4v R;
            if constexpr (DEF) {
                float ox = offp[((size_t)(b * 18 + n) * OH + i) * OW + j];
                float oy = offp[((size_t)(b * 18 + 9 + n) * OH + i) * OW + j];
                float px = (float)(i * S + n / 3) + ox;
                float py = (float)(j * S + n % 3) + oy;
                int qx0 = (int)floorf(px), qy0 = (int)floorf(py);
                int x0 = min(max(qx0, 0), Hp - 1), x1 = min(max(qx0 + 1, 0), Hp - 1);
                int y0 = min(max(qy0, 0), Wp - 1), y1 = min(max(qy0 + 1, 0), Wp - 1);
                float pxc = fminf(fmaxf(px, 0.f), (float)(Hp - 1));
                float pyc = fminf(fmaxf(py, 0.f), (float)(Wp - 1));
                float gx0 = 1.f + ((float)x0 - pxc), gx1 = 1.f - ((float)x1 - pxc);
                float gy0 = 1.f + ((float)y0 - pyc), gy1 = 1.f - ((float)y1 - pyc);
                int u0 = x0 - 1, u1 = x1 - 1, v0 = y0 - 1, v1 = y1 - 1;
                bool k0 = (u0 >= 0 && u0 < H && v0 >= 0 && v0 < W);
                bool k1 = (u1 >= 0 && u1 < H && v1 >= 0 && v1 < W);
                bool k2 = (u0 >= 0 && u0 < H && v1 >= 0 && v1 < W);
                bool k3 = (u1 >= 0 && u1 < H && v0 >= 0 && v0 < W);
                int t0 = k0 ? (u0 * W + v0) * C : 0;  float w0 = k0 ? gx0 * gy0 : 0.f;
                int t1 = k1 ? (u1 * W + v1) * C : 0;  float w1 = k1 ? gx1 * gy1 : 0.f;
                int t2 = k2 ? (u0 * W + v1) * C : 0;  float w2 = k2 ? gx0 * gy1 : 0.f;
                int t3 = k3 ? (u1 * W + v0) * C : 0;  float w3 = k3 ? gx1 * gy0 : 0.f;
                i4v A = *(const i4v*)(xb + t0);
                i4v Bv = *(const i4v*)(xb + t1);
                i4v Cv = *(const i4v*)(xb + t2);
                i4v Dv = *(const i4v*)(xb + t3);
                #pragma unroll
                for (int e = 0; e < 4; ++e) {
                    float lo = w0 * blo(A[e]);
                    lo = fmaf(w1, blo(Bv[e]), lo);
                    lo = fmaf(w2, blo(Cv[e]), lo);
                    lo = fmaf(w3, blo(Dv[e]), lo);
                    float hi = w0 * bhi(A[e]);
                    hi = fmaf(w1, bhi(Bv[e]), hi);
                    hi = fmaf(w2, bhi(Cv[e]), hi);
                    hi = fmaf(w3, bhi(Dv[e]), hi);
                    R[e] = pkbf(lo, hi);
                }
            } else {
                int u = i * S - 1 + n / 3, vv = j * S - 1 + n % 3;
                bool ok = (u >= 0 && u < H && vv >= 0 && vv < W);
                if (ok) R = *(const i4v*)(xb + (u * W + vv) * C);
                else    R = (i4v){0, 0, 0, 0};
            }
            *(i4v*)&xo[buf][pix * CP + gl * 8] = R;
        }
    };

    auto load_wf = [&](int n, short8 (*wf)[OT]) {
        #pragma unroll
        for (int ch = 0; ch < KCH; ++ch)
            #pragma unroll
            for (int t = 0; t < OT; ++t)
                wf[ch][t] = *(const short8*)(wq + (size_t)(obase + t * 16 + m16) * K
                                             + n * C + ch * 32 + quad * 8);
    };

    f32x4 acc[ST][OT];
    #pragma unroll
    for (int st = 0; st < ST; ++st)
        #pragma unroll
        for (int t = 0; t < OT; ++t) acc[st][t] = (f32x4){0.f, 0.f, 0.f, 0.f};

    short8 wfA[KCH][OT], wfB[KCH][OT];
    do_gather(0, 0);
    load_wf(0, wfA);
    __syncthreads();

    for (int n = 0; n < 9; ++n) {
        const int cur = n & 1;
        if (n < 8) {
            do_gather(n + 1, cur ^ 1);
            load_wf(n + 1, wfB);
        }
        #pragma unroll
        for (int ch = 0; ch < KCH; ++ch)
            #pragma unroll
            for (int st = 0; st < ST; ++st) {
                short8 bf = *(const short8*)&xo[cur][(pixbase + st * 16 + m16) * CP
                                                    + ch * 32 + quad * 8];
                #pragma unroll
                for (int t = 0; t < OT; ++t)
                    acc[st][t] = __builtin_amdgcn_mfma_f32_16x16x32_bf16(
                        wfA[ch][t], bf, acc[st][t], 0, 0, 0);
            }
        if (n < 8) {
            #pragma unroll
            for (int ch = 0; ch < KCH; ++ch)
                #pragma unroll
                for (int t = 0; t < OT; ++t) wfA[ch][t] = wfB[ch][t];
        }
        __syncthreads();
    }

    if constexpr (BN) {
        unsigned short* outw = (unsigned short*)outv;
        #pragma unroll
        for (int st = 0; st < ST; ++st) {
            const int p = p0 + pixbase + st * 16 + m16;
            #pragma unroll
            for (int t = 0; t < OT; ++t) {
                int o = obase + t * 16 + quad * 4;
                ushort4 s;
                #pragma unroll
                for (int rr = 0; rr < 4; ++rr)
                    ((unsigned short*)&s)[rr] =
                        f2bf(fmaxf(fmaf(acc[st][t][rr], scb[o + rr], shb[o + rr]), 0.f));
                *(ushort4*)(outw + (size_t)p * OPAD + o) = s;
            }
        }
    } else {
        float* outf = (float*)outv;
        #pragma unroll
        for (int st = 0; st < ST; ++st) {
            const int p = p0 + pixbase + st * 16 + m16;
            const int b = p / OHW, rem = p % OHW;
            const int i = rem / OW, j = rem % OW;
            #pragma unroll
            for (int t = 0; t < OT; ++t)
                #pragma unroll
                for (int rr = 0; rr < 4; ++rr) {
                    int o = obase + t * 16 + quad * 4 + rr;
                    if (o < OREAL)
                        outf[((size_t)(b * 18 + o) * OH + i) * OW + j] =
                            acc[st][t][rr] + scb[o];
                }
        }
    }
}

// ---------------- global avg pool (8x8, NHWC bf16) + FC 128->100 ----------------
__global__ __launch_bounds__(128)
void pool_fc(const unsigned short* __restrict__ h4, const float* __restrict__ wcls,
             const float* __restrict__ bcls, float* __restrict__ out)
{
    __shared__ float pool[128];
    int b = blockIdx.x;
    int tid = threadIdx.x;
    const unsigned short* src = h4 + (size_t)b * 8192;
    float s = 0.f;
    #pragma unroll
    for (int t = 0; t < 64; ++t)
        s += __builtin_bit_cast(float, (unsigned)src[t * 128 + tid] << 16);
    pool[tid] = s * (1.f / 64.f);
    __syncthreads();
    if (tid < 100) {
        float acc = bcls[tid];
        const float* wr = wcls + tid * 128;
        #pragma unroll
        for (int c = 0; c < 128; ++c) acc = fmaf(pool[c], wr[c], acc);
        out[(size_t)b * 100 + tid] = acc;
    }
}

extern "C" void kernel_launch(void* const* d_in, const int* in_sizes, int n_in,
                              void* d_out, int out_size, void* d_ws, size_t ws_size,
                              hipStream_t stream)
{
    const float* x    = (const float*)d_in[0];
    const float* w1   = (const float*)d_in[1];
    const float* b1   = (const float*)d_in[2];
    const float* g1   = (const float*)d_in[3];
    const float* be1  = (const float*)d_in[4];
    const float* m1   = (const float*)d_in[5];
    const float* v1   = (const float*)d_in[6];
    const float* wp2  = (const float*)d_in[7];
    const float* bp2  = (const float*)d_in[8];
    const float* wc2  = (const float*)d_in[9];
    const float* g2   = (const float*)d_in[10];
    const float* be2  = (const float*)d_in[11];
    const float* m2   = (const float*)d_in[12];
    const float* v2   = (const float*)d_in[13];
    const float* wp3  = (const float*)d_in[14];
    const float* bp3  = (const float*)d_in[15];
    const float* wc3  = (const float*)d_in[16];
    const float* g3   = (const float*)d_in[17];
    const float* be3  = (const float*)d_in[18];
    const float* m3   = (const float*)d_in[19];
    const float* v3   = (const float*)d_in[20];
    const float* wp4  = (const float*)d_in[21];
    const float* bp4  = (const float*)d_in[22];
    const float* wc4  = (const float*)d_in[23];
    const float* g4   = (const float*)d_in[24];
    const float* be4  = (const float*)d_in[25];
    const float* m4   = (const float*)d_in[26];
    const float* v4   = (const float*)d_in[27];
    const float* wcls = (const float*)d_in[28];
    const float* bcls = (const float*)d_in[29];
    float* out = (float*)d_out;

    float* ws  = (float*)d_ws;
    float* off = ws;                               // fp32 NCHW, max 1,179,648 (reused)
    unsigned short* h1 = (unsigned short*)(off + 1179648);  // NHWC bf16 256*1024*32
    unsigned short* h2 = h1 + 8388608;             // 256*256*64
    unsigned short* h3 = h2 + 4194304;             // 256*256*128
    unsigned short* h4 = h3 + 8388608;             // 256*64*128
    unsigned short* wc2b = h4 + 2097152;           // 64*288
    unsigned short* wc3b = wc2b + 18432;           // 128*576
    unsigned short* wc4b = wc3b + 73728;           // 128*1152
    unsigned short* wp2b = wc4b + 147456;          // 32*288
    unsigned short* wp3b = wp2b + 9216;            // 32*576
    unsigned short* wp4b = wp3b + 18432;           // 32*1152
    unsigned short* wq1  = wp4b + 36864;           // 32*32
    (void)ws_size; (void)in_sizes; (void)n_in; (void)out_size;

    CvtArgs ca;
    ca.s[0] = { wc2, wc2b, 64, 32, 288, 18432 };
    ca.s[1] = { wc3, wc3b, 128, 64, 576, 92160 };
    ca.s[2] = { wc4, wc4b, 128, 128, 1152, 239616 };
    ca.s[3] = { wp2, wp2b, 18, 32, 288, 248832 };
    ca.s[4] = { wp3, wp3b, 18, 64, 576, 267264 };
    ca.s[5] = { wp4, wp4b, 18, 128, 1152, 304128 };
    ca.s[6] = { w1, wq1, 32, 3, 32, 305152 };
    cvt_all<<<1192, 256, 0, stream>>>(ca);

    // Layer 1
    conv1_tile<<<1024, 256, 0, stream>>>(x, wq1, b1, g1, be1, m1, v1, h1);

    // Layer 2: 32x32 -> 16x16, stride 2, C=32 -> O=64  (1024 blocks each)
    dconv<32, 18, 32, 32, 32, 16, 16, 2, 64, false, false><<<1024, 256, 0, stream>>>(
        h1, nullptr, wp2b, bp2, nullptr, nullptr, nullptr, off);
    dconv<32, 64, 64, 32, 32, 16, 16, 2, 64, true, true><<<1024, 256, 0, stream>>>(
        h1, off, wc2b, g2, be2, m2, v2, h2);

    // Layer 3: 16x16 -> 16x16, stride 1, C=64 -> O=128  (1024 blocks each)
    dconv<64, 18, 32, 16, 16, 16, 16, 1, 64, false, false><<<1024, 256, 0, stream>>>(
        h2, nullptr, wp3b, bp3, nullptr, nullptr, nullptr, off);
    dconv<64, 128, 128, 16, 16, 16, 16, 1, 64, true, true><<<1024, 256, 0, stream>>>(
        h2, off, wc3b, g3, be3, m3, v3, h3);

    // Layer 4: 16x16 -> 8x8, stride 2, C=128 -> O=128  (512 blocks each, MTILE=32)
    dconv<128, 18, 32, 16, 16, 8, 8, 2, 32, false, false><<<512, 256, 0, stream>>>(
        h3, nullptr, wp4b, bp4, nullptr, nullptr, nullptr, off);
    dconv<128, 128, 128, 16, 16, 8, 8, 2, 32, true, true><<<512, 256, 0, stream>>>(
        h3, off, wc4b, g4, be4, m4, v4, h4);

    // Pool + FC
    pool_fc<<<256, 128, 0, stream>>>(h4, wcls, bcls, out);
}